// Round 8
// baseline (1131.753 us; speedup 1.0000x reference)
//
#include <hip/hip_runtime.h>

#define NN 100000
#define NE 1600000
#define BN_EPS 1e-5f

// CSR binning parameters
#define BSH 7
#define BSZ (1 << BSH)   // 128 dsts per bucket
#define NBUCK 782        // divup(NN, BSZ)
#define NC 192           // edge chunks
#define CE 8334          // divup(NE, NC)

typedef _Float16 half1;
typedef _Float16 half4 __attribute__((ext_vector_type(4)));
typedef _Float16 h8 __attribute__((ext_vector_type(8)));
typedef float f4 __attribute__((ext_vector_type(4)));
typedef float f8 __attribute__((ext_vector_type(8)));

static inline int divup(int a, int b) { return (a + b - 1) / b; }

// per-edge source weight from packed entry: src in [0:17), deg_src in [17:32)
__device__ __forceinline__ float wsrc(unsigned int q) {
    unsigned int dg = q >> 17;
    return dg ? rsqrtf((float)dg) : 0.f;
}

// ---------------- preprocessing (no global atomics) ----------------

__global__ void histb_kernel(const int* __restrict__ dst, int* __restrict__ hist_g) {
    __shared__ int h[NBUCK];
    int c = blockIdx.x;
    for (int i = threadIdx.x; i < NBUCK; i += blockDim.x) h[i] = 0;
    __syncthreads();
    int e0 = c * CE, e1 = min(e0 + CE, NE);
    for (int e = e0 + threadIdx.x; e < e1; e += blockDim.x)
        atomicAdd(&h[dst[e] >> BSH], 1);
    __syncthreads();
    for (int i = threadIdx.x; i < NBUCK; i += blockDim.x) hist_g[c * NBUCK + i] = h[i];
}

__global__ void bscan1_kernel(const int* __restrict__ hist_g, int* __restrict__ bucket_start,
                              int* __restrict__ row_ptr) {
    __shared__ int sh[1024];
    int t = threadIdx.x;
    int tot = 0;
    if (t < NBUCK)
        for (int c = 0; c < NC; ++c) tot += hist_g[c * NBUCK + t];
    sh[t] = (t < NBUCK) ? tot : 0;
    __syncthreads();
    for (int off = 1; off < 1024; off <<= 1) {
        int v = (t >= off) ? sh[t - off] : 0;
        __syncthreads();
        sh[t] += v;
        __syncthreads();
    }
    if (t < NBUCK) bucket_start[t] = sh[t] - tot;
    if (t == 0) { bucket_start[NBUCK] = NE; row_ptr[NN] = NE; }
}

__global__ void boff_kernel(const int* __restrict__ bucket_start, const int* __restrict__ hist_g,
                            int* __restrict__ off_g) {
    int b = blockIdx.x * blockDim.x + threadIdx.x;
    if (b >= NBUCK) return;
    int run = bucket_start[b];
#pragma unroll 4
    for (int c = 0; c < NC; ++c) {
        off_g[c * NBUCK + b] = run;
        run += hist_g[c * NBUCK + b];
    }
}

__global__ void binscatter_kernel(const int* __restrict__ src, const int* __restrict__ dst,
                                  const int* __restrict__ off_g, unsigned int* __restrict__ tmp) {
    __shared__ int off_l[NBUCK];
    int myx = blockIdx.x & 7;
    int c = blockIdx.x >> 3;
    for (int i = threadIdx.x; i < NBUCK; i += blockDim.x)
        off_l[i] = ((i & 7) == myx) ? off_g[c * NBUCK + i] : 0;
    __syncthreads();
    int e0 = c * CE, e1 = min(e0 + CE, NE);
    for (int e = e0 + threadIdx.x; e < e1; e += blockDim.x) {
        int d = dst[e];
        int b = d >> BSH;
        if ((b & 7) != myx) continue;
        int s = src[e];
        int pos = atomicAdd(&off_l[b], 1);
        tmp[pos] = (unsigned int)s | ((unsigned int)(d & (BSZ - 1)) << 25);
    }
}

__global__ void finalize_kernel(const unsigned int* __restrict__ tmp,
                                const int* __restrict__ bucket_start,
                                int* __restrict__ row_ptr, int* __restrict__ deg,
                                unsigned int* __restrict__ cw) {
    __shared__ int cnt[BSZ], sc[BSZ], cur[BSZ];
    int b = blockIdx.x, t = threadIdx.x;
    int e0 = bucket_start[b], e1 = bucket_start[b + 1];
    if (t < BSZ) cnt[t] = 0;
    __syncthreads();
    for (int e = e0 + t; e < e1; e += blockDim.x) atomicAdd(&cnt[tmp[e] >> 25], 1);
    __syncthreads();
    if (t < BSZ) sc[t] = cnt[t];
    __syncthreads();
    for (int off = 1; off < BSZ; off <<= 1) {
        int v = (t >= off && t < BSZ) ? sc[t - off] : 0;
        __syncthreads();
        if (t < BSZ) sc[t] += v;
        __syncthreads();
    }
    if (t < BSZ) {
        int p = e0 + sc[t] - cnt[t];
        cur[t] = p;
        int nd = (b << BSH) + t;
        if (nd < NN) { row_ptr[nd] = p; deg[nd] = cnt[t]; }
    }
    __syncthreads();
    for (int e = e0 + t; e < e1; e += blockDim.x) {
        unsigned int r = tmp[e];
        int ld = r >> 25;
        int k = atomicAdd(&cur[ld], 1);
        cw[k] = r & 0x1FFFFu;
    }
}

__global__ void packdeg_kernel(unsigned int* __restrict__ cw, const int* __restrict__ deg) {
    int e = blockIdx.x * blockDim.x + threadIdx.x;
    if (e >= NE) return;
    unsigned int q = cw[e];
    int dg = deg[q];
    if (dg > 32767) dg = 32767;
    cw[e] = q | ((unsigned int)dg << 17);
}

// ---------------- fp16 converts for MFMA ----------------

__global__ void cvtx_kernel(const float4* __restrict__ X, half4* __restrict__ Xh, int tot4) {
    int i = blockIdx.x * blockDim.x + threadIdx.x;
    if (i >= tot4) return;
    float4 v = X[i];
    half4 h;
    h.x = (half1)v.x; h.y = (half1)v.y; h.z = (half1)v.z; h.w = (half1)v.w;
    Xh[i] = h;
}

// Wt[og][kd] = W1[og>>6][kd][og&63], fp16 ; Wt is [512][128]
__global__ void transw_kernel(const float* __restrict__ W, half1* __restrict__ Wt) {
    int i = blockIdx.x * blockDim.x + threadIdx.x;
    if (i >= 512 * 128) return;
    int kd = i >> 9;
    int og = i & 511;
    int k = og >> 6, o = og & 63;
    Wt[(size_t)og * 128 + kd] = (half1)W[((size_t)k * 128 + kd) * 64 + o];
}

// ---------------- W padding ----------------
__global__ void padw_kernel(const float* __restrict__ src, float* __restrict__ dst,
                            int K, int dins, int douts, int dind, int doutd) {
    int i = blockIdx.x * blockDim.x + threadIdx.x;
    int tot = K * dind * doutd;
    if (i >= tot) return;
    int o = i % doutd;
    int r = i / doutd;
    int dd = r % dind;
    int k = r / dind;
    dst[i] = (dd < dins && o < douts) ? src[((size_t)k * dins + dd) * douts + o] : 0.f;
}

// ---------------- Clenshaw prop, QUARTERED dim-64 states ----------------
// All dim-64 buffers use planar-quarter layout: [q][node][16 halves] per quarter,
// quarter plane q at byte offset q*NN*32. One kernel launch per quarter: the
// gather working set is 3.2 MB -> resident in each XCD's 4 MB L2.
// Thread (nd, j): handles global dims 16q + 8j .. +7 (bn_* pre-offset by 16q).
__global__ void prophq_kernel(const h8* __restrict__ featq, const h8* __restrict__ subq,
                              const h8* __restrict__ addq, h8* __restrict__ outhq,
                              f8* __restrict__ outfq,
                              const int* __restrict__ row_ptr, const unsigned int* __restrict__ cw,
                              int n, float scale, int has_sub, int bnrelu,
                              const float* __restrict__ bn_g, const float* __restrict__ bn_b,
                              const float* __restrict__ bn_m, const float* __restrict__ bn_v) {
    int idx = blockIdx.x * blockDim.x + threadIdx.x;
    if (idx >= n * 2) return;
    int nd = idx >> 1;
    int j = idx & 1;
    int e0 = row_ptr[nd], e1 = row_ptr[nd + 1];
    f8 a0 = {0.f, 0.f, 0.f, 0.f, 0.f, 0.f, 0.f, 0.f}, a1 = a0, a2 = a0, a3 = a0;
    int e = e0;
    for (; e + 4 <= e1; e += 4) {
        unsigned int q0 = __builtin_nontemporal_load(&cw[e]);
        unsigned int q1 = __builtin_nontemporal_load(&cw[e + 1]);
        unsigned int q2 = __builtin_nontemporal_load(&cw[e + 2]);
        unsigned int q3 = __builtin_nontemporal_load(&cw[e + 3]);
        f8 v0 = __builtin_convertvector(featq[(size_t)(q0 & 0x1FFFFu) * 2 + j], f8);
        f8 v1 = __builtin_convertvector(featq[(size_t)(q1 & 0x1FFFFu) * 2 + j], f8);
        f8 v2 = __builtin_convertvector(featq[(size_t)(q2 & 0x1FFFFu) * 2 + j], f8);
        f8 v3 = __builtin_convertvector(featq[(size_t)(q3 & 0x1FFFFu) * 2 + j], f8);
        a0 += wsrc(q0) * v0;
        a1 += wsrc(q1) * v1;
        a2 += wsrc(q2) * v2;
        a3 += wsrc(q3) * v3;
    }
    for (; e < e1; ++e) {
        unsigned int q = cw[e];
        a0 += wsrc(q) * __builtin_convertvector(featq[(size_t)(q & 0x1FFFFu) * 2 + j], f8);
    }
    int degd = e1 - e0;
    float ms = (degd > 0) ? -scale * rsqrtf((float)degd) : 0.f;
    f8 r = ((a0 + a1) + (a2 + a3)) * ms;
    if (has_sub) r -= __builtin_convertvector(__builtin_nontemporal_load(&subq[idx]), f8);
    r += __builtin_convertvector(__builtin_nontemporal_load(&addq[idx]), f8);
    if (bnrelu) {
#pragma unroll
        for (int c = 0; c < 8; ++c) {
            int o = j * 8 + c;
            float sc = bn_g[o] * rsqrtf(bn_v[o] + BN_EPS);
            r[c] = fmaxf(fmaf(r[c] - bn_m[o], sc, bn_b[o]), 0.f);
        }
    }
    if (outfq) {
        outfq[(size_t)nd * 8 + j] = r;   // row-major fp32, pre-offset by q*2 f8
    } else {
        outhq[idx] = __builtin_convertvector(r, h8);
    }
}

// ---------------- Clenshaw prop, half4 gathers — small dims (layers 2-4) ----------
__global__ void proph_kernel(const half4* __restrict__ feat, const half4* __restrict__ sub,
                             const half4* __restrict__ add, half4* __restrict__ outh,
                             f4* __restrict__ outf,
                             const int* __restrict__ row_ptr, const unsigned int* __restrict__ cw,
                             int n, int dim4, float scale, int has_sub,
                             int bnrelu, int used,
                             const float* __restrict__ bn_g, const float* __restrict__ bn_b,
                             const float* __restrict__ bn_m, const float* __restrict__ bn_v) {
    int idx = blockIdx.x * blockDim.x + threadIdx.x;
    if (idx >= n * dim4) return;
    int nd = idx / dim4;
    int f = idx - nd * dim4;
    int e0 = row_ptr[nd], e1 = row_ptr[nd + 1];
    f4 a0 = {0.f, 0.f, 0.f, 0.f}, a1 = a0, a2 = a0, a3 = a0;
    int e = e0;
    for (; e + 4 <= e1; e += 4) {
        unsigned int q0 = cw[e], q1 = cw[e + 1], q2 = cw[e + 2], q3 = cw[e + 3];
        f4 v0 = __builtin_convertvector(feat[(size_t)(q0 & 0x1FFFFu) * dim4 + f], f4);
        f4 v1 = __builtin_convertvector(feat[(size_t)(q1 & 0x1FFFFu) * dim4 + f], f4);
        f4 v2 = __builtin_convertvector(feat[(size_t)(q2 & 0x1FFFFu) * dim4 + f], f4);
        f4 v3 = __builtin_convertvector(feat[(size_t)(q3 & 0x1FFFFu) * dim4 + f], f4);
        a0 += wsrc(q0) * v0;
        a1 += wsrc(q1) * v1;
        a2 += wsrc(q2) * v2;
        a3 += wsrc(q3) * v3;
    }
    for (; e < e1; ++e) {
        unsigned int q = cw[e];
        a0 += wsrc(q) * __builtin_convertvector(feat[(size_t)(q & 0x1FFFFu) * dim4 + f], f4);
    }
    int degd = e1 - e0;
    float ms = (degd > 0) ? -scale * rsqrtf((float)degd) : 0.f;
    f4 r = ((a0 + a1) + (a2 + a3)) * ms;
    if (has_sub) r -= __builtin_convertvector(sub[idx], f4);
    r += __builtin_convertvector(__builtin_nontemporal_load(&add[idx]), f4);
    if (bnrelu) {
#pragma unroll
        for (int c = 0; c < 4; ++c) {
            int o = f * 4 + c;
            if (o < used) {
                float sc = bn_g[o] * rsqrtf(bn_v[o] + BN_EPS);
                r[c] = fmaxf(fmaf(r[c] - bn_m[o], sc, bn_b[o]), 0.f);
            } else r[c] = 0.f;
        }
    }
    if (outf) {
        outf[idx] = r;
    } else {
        half4 h;
        h.x = (half1)r.x; h.y = (half1)r.y; h.z = (half1)r.z; h.w = (half1)r.w;
        outh[idx] = h;
    }
}

// layer-4 final: fp16 gathers/streams at stride 12 (dim4=3), fp32 out at stride 10
__global__ void propl_kernel(const half4* __restrict__ feat, const half4* __restrict__ sub,
                             const half4* __restrict__ add, float* __restrict__ out,
                             const int* __restrict__ row_ptr, const unsigned int* __restrict__ cw,
                             int n) {
    int idx = blockIdx.x * blockDim.x + threadIdx.x;
    if (idx >= n * 3) return;
    int nd = idx / 3;
    int f = idx - nd * 3;
    int e0 = row_ptr[nd], e1 = row_ptr[nd + 1];
    f4 a0 = {0.f, 0.f, 0.f, 0.f}, a1 = a0, a2 = a0, a3 = a0;
    int e = e0;
    for (; e + 4 <= e1; e += 4) {
        unsigned int q0 = cw[e], q1 = cw[e + 1], q2 = cw[e + 2], q3 = cw[e + 3];
        a0 += wsrc(q0) * __builtin_convertvector(feat[(size_t)(q0 & 0x1FFFFu) * 3 + f], f4);
        a1 += wsrc(q1) * __builtin_convertvector(feat[(size_t)(q1 & 0x1FFFFu) * 3 + f], f4);
        a2 += wsrc(q2) * __builtin_convertvector(feat[(size_t)(q2 & 0x1FFFFu) * 3 + f], f4);
        a3 += wsrc(q3) * __builtin_convertvector(feat[(size_t)(q3 & 0x1FFFFu) * 3 + f], f4);
    }
    for (; e < e1; ++e) {
        unsigned int q = cw[e];
        a0 += wsrc(q) * __builtin_convertvector(feat[(size_t)(q & 0x1FFFFu) * 3 + f], f4);
    }
    int degd = e1 - e0;
    float ms = (degd > 0) ? -rsqrtf((float)degd) : 0.f;
    f4 r = ((a0 + a1) + (a2 + a3)) * ms;
    r -= __builtin_convertvector(sub[idx], f4);
    r += __builtin_convertvector(add[idx], f4);
    int o = f * 4;
    float* orow = out + (size_t)nd * 10;
    if (o + 0 < 10) orow[o + 0] = r.x;
    if (o + 1 < 10) orow[o + 1] = r.y;
    if (o + 2 < 10) orow[o + 2] = r.z;
    if (o + 3 < 10) orow[o + 3] = r.w;
}

// ---------------- layer-1 GEMM via MFMA (8 waves = 8 k-slices, 64-node tile) --------
// R5 structure (73us, 0 bank conflicts); epilogue writes QUARTERED planes:
// CB layout [k][q][node][16 halves].
#define LSTR 68
__global__ __launch_bounds__(512) void gemm_mfma_kernel(
        const half1* __restrict__ Xh, const half1* __restrict__ Wt,
        const float* __restrict__ bias, half1* __restrict__ CB, int n) {
    __shared__ half1 lds[8 * 32 * LSTR];  // 34816 B
    int lane = threadIdx.x & 63;
    int ks = threadIdx.x >> 6;   // 0..7
    int m16 = lane & 15;
    int quad = lane >> 4;
    int ntile = blockIdx.x * 64;

    f4 acc[4][4];
#pragma unroll
    for (int nt = 0; nt < 4; ++nt)
#pragma unroll
        for (int i = 0; i < 4; ++i) acc[nt][i] = (f4){0.f, 0.f, 0.f, 0.f};

#pragma unroll
    for (int kc = 0; kc < 4; ++kc) {
        int koff = kc * 32 + quad * 8;
        h8 a[4];
#pragma unroll
        for (int i = 0; i < 4; ++i)
            a[i] = *(const h8*)(Wt + (size_t)(ks * 64 + i * 16 + m16) * 128 + koff);
        h8 b[4];
#pragma unroll
        for (int nt = 0; nt < 4; ++nt) {
            int node = min(ntile + nt * 16 + m16, n - 1);
            b[nt] = *(const h8*)(Xh + (size_t)node * 128 + koff);
        }
#pragma unroll
        for (int nt = 0; nt < 4; ++nt)
#pragma unroll
            for (int i = 0; i < 4; ++i)
                acc[nt][i] = __builtin_amdgcn_mfma_f32_16x16x32_f16(a[i], b[nt], acc[nt][i], 0, 0, 0);
    }

    half1* slab = lds + (size_t)ks * 32 * LSTR;
    int nl = lane >> 1;     // 0..31
    int jh = lane & 1;      // 0..1
#pragma unroll
    for (int hh = 0; hh < 2; ++hh) {
        // stage 32 nodes (nt = 2*hh, 2*hh+1) into this wave's slab
#pragma unroll
        for (int p = 0; p < 2; ++p) {
            int nt = hh * 2 + p;
            int node_l = p * 16 + m16;
#pragma unroll
            for (int i = 0; i < 4; ++i) {
                int ob = i * 16 + quad * 4;
                f4 v = acc[nt][i];
                if (ks == 0) {
                    const f4 b4 = *(const f4*)(bias + ob);
                    v += b4;
                }
                half4 h;
                h.x = (half1)v[0]; h.y = (half1)v[1]; h.z = (half1)v[2]; h.w = (half1)v[3];
                *(half4*)(slab + node_l * LSTR + ob) = h;
            }
        }
        asm volatile("s_waitcnt lgkmcnt(0)" ::: "memory");  // cross-lane RAW within wave
        // quartered copy-out: per quarter q, 2 lanes per node write 32B chunks;
        // wave writes 32 nodes x 32B = 1KB contiguous per store instruction
#pragma unroll
        for (int q = 0; q < 4; ++q) {
            int node = ntile + hh * 32 + nl;
            if (node < n) {
                h8 v = *(const h8*)(slab + nl * LSTR + q * 16 + jh * 8);
                *((h8*)CB + ((size_t)(ks * 4 + q) * n + node) * 2 + jh) = v;
            }
        }
        // DS ops in-order per wave: hh=1 restage cannot pass the reads above.
    }
}

// ---------------- small-layer GEMM: block = KK waves, wave k, lane = node -------------
template <int KK, int DIN4, int NACC>
__global__ void gemm_smallw_kernel(const float* __restrict__ X, const float* __restrict__ Wp,
                                   const float* __restrict__ bias, int dout,
                                   half4* __restrict__ CB, int n) {
    int lane = threadIdx.x & 63;
    int k = __builtin_amdgcn_readfirstlane((int)(threadIdx.x >> 6));
    int node0 = blockIdx.x * 64 + lane;
    int node = min(node0, n - 1);
    f4 acc[NACC];
#pragma unroll
    for (int i = 0; i < NACC; ++i) {
        f4 v = {0.f, 0.f, 0.f, 0.f};
        if (k == 0 && bias) {
#pragma unroll
            for (int c = 0; c < 4; ++c) {
                int o = i * 4 + c;
                v[c] = (o < dout) ? bias[o] : 0.f;
            }
        }
        acc[i] = v;
    }
    const f4* Xr = (const f4*)(X + (size_t)node * (DIN4 * 4));
    const f4* Wk = (const f4*)(Wp + (size_t)k * (DIN4 * 4) * (NACC * 4));
    for (int d4 = 0; d4 < DIN4; ++d4) {
        f4 xv = Xr[d4];
#pragma unroll
        for (int j = 0; j < 4; ++j) {
            float xs = xv[j];
#pragma unroll
            for (int i = 0; i < NACC; ++i)
                acc[i] += xs * Wk[(d4 * 4 + j) * NACC + i];
        }
    }
    if (node0 < n) {
        size_t base = ((size_t)k * n + node) * NACC;
#pragma unroll
        for (int i = 0; i < NACC; ++i) {
            half4 h;
            h.x = (half1)acc[i].x; h.y = (half1)acc[i].y;
            h.z = (half1)acc[i].z; h.w = (half1)acc[i].w;
            CB[base + i] = h;
        }
    }
}

// ---------------- host driver ----------------

extern "C" void kernel_launch(void* const* d_in, const int* in_sizes, int n_in,
                              void* d_out, int out_size, void* d_ws, size_t ws_size,
                              hipStream_t stream) {
    const float* x  = (const float*)d_in[0];
    const int*   ei = (const int*)d_in[1];
    const float* Wl[4] = {(const float*)d_in[2], (const float*)d_in[4],
                          (const float*)d_in[6], (const float*)d_in[8]};
    const float* bl[4] = {(const float*)d_in[3], (const float*)d_in[5],
                          (const float*)d_in[7], (const float*)d_in[9]};
    const float* bn[3][4];
    for (int l = 0; l < 3; ++l)
        for (int j = 0; j < 4; ++j)
            bn[l][j] = (const float*)d_in[10 + 4 * l + j];

    char* ws = (char*)d_ws;
    size_t off = 0;
    auto alloc = [&](size_t bytes) -> void* {
        void* p = (void*)(ws + off);
        off = (off + bytes + 255) & ~(size_t)255;
        return p;
    };
    int*   deg      = (int*)alloc(NN * 4);
    int*   row_ptr  = (int*)alloc((NN + 1) * 4);
    int*   bstart   = (int*)alloc((NBUCK + 1) * 4);
    unsigned int* cw = (unsigned int*)alloc((size_t)NE * 4);
    half1* CB1h    = (half1*)alloc((size_t)8 * NN * 64 * 2);
    half1* CBsh    = (half1*)alloc((size_t)6 * NN * 20 * 2);
    half1* S0      = (half1*)alloc((size_t)NN * 64 * 2);
    half1* S1      = (half1*)alloc((size_t)NN * 64 * 2);
    half1* S2      = (half1*)alloc((size_t)NN * 64 * 2);
    float* H1f     = (float*)alloc((size_t)NN * 64 * 4);
    float* H2f     = (float*)alloc((size_t)NN * 20 * 4);
    float* H3f     = (float*)alloc((size_t)NN * 12 * 4);
    float* Wp2     = (float*)alloc((size_t)6 * 64 * 20 * 4);
    float* Wp3     = (float*)alloc((size_t)4 * 20 * 12 * 4);
    float* Wp4     = (float*)alloc((size_t)4 * 12 * 12 * 4);
    half1* Xh      = (half1*)alloc((size_t)NN * 128 * 2);
    half1* Wt1     = (half1*)alloc((size_t)512 * 128 * 2);

    // CSR-build scratch aliased into CB1h (consumed before gemm_mfma writes it):
    unsigned int* tmp = (unsigned int*)CB1h;                // 6.4 MB
    int* hist_g = (int*)((char*)CB1h + (16u << 20));        // NC*NBUCK*4 = 600 KB
    int* off_g  = hist_g + NC * NBUCK;                      // 600 KB

    const int* srcp = ei;
    const int* dstp = ei + NE;
    const int NB = divup(NN, 64);

    histb_kernel<<<NC, 256, 0, stream>>>(dstp, hist_g);
    bscan1_kernel<<<1, 1024, 0, stream>>>(hist_g, bstart, row_ptr);
    boff_kernel<<<divup(NBUCK, 256), 256, 0, stream>>>(bstart, hist_g, off_g);
    binscatter_kernel<<<NC * 8, 256, 0, stream>>>(srcp, dstp, off_g, tmp);
    finalize_kernel<<<NBUCK, 256, 0, stream>>>(tmp, bstart, row_ptr, deg, cw);
    packdeg_kernel<<<divup(NE, 256), 256, 0, stream>>>(cw, deg);

    cvtx_kernel<<<divup(NN * 32, 256), 256, 0, stream>>>((const float4*)x, (half4*)Xh, NN * 32);
    transw_kernel<<<divup(512 * 128, 256), 256, 0, stream>>>(Wl[0], Wt1);
    padw_kernel<<<divup(6 * 64 * 20, 256), 256, 0, stream>>>(Wl[1], Wp2, 6, 64, 18, 64, 20);
    padw_kernel<<<divup(4 * 20 * 12, 256), 256, 0, stream>>>(Wl[2], Wp3, 4, 18, 9, 20, 12);
    padw_kernel<<<divup(4 * 12 * 12, 256), 256, 0, stream>>>(Wl[3], Wp4, 4, 9, 10, 12, 12);

    // dim-64 prop, quartered: 4 passes, each restricted to a 3.2MB quarter plane
    auto prop1 = [&](const half1* feat, const half1* sub, const half1* add,
                     half1* outh, float* outf, float scale, int bnrelu,
                     const float* g, const float* bb, const float* m, const float* v) {
        for (int q = 0; q < 4; ++q) {
            const h8* fq = (const h8*)feat + (size_t)q * NN * 2;
            const h8* sq = sub ? (const h8*)sub + (size_t)q * NN * 2 : nullptr;
            const h8* aq = (const h8*)add + (size_t)q * NN * 2;
            h8* oq = outh ? (h8*)outh + (size_t)q * NN * 2 : nullptr;
            f8* ofq = outf ? (f8*)outf + q * 2 : nullptr;
            prophq_kernel<<<divup(NN * 2, 256), 256, 0, stream>>>(
                fq, sq, aq, oq, ofq, row_ptr, cw, NN, scale,
                sub != nullptr, bnrelu,
                g ? g + 16 * q : nullptr, bb ? bb + 16 * q : nullptr,
                m ? m + 16 * q : nullptr, v ? v + 16 * q : nullptr);
        }
    };
    // small-dim prop (half4 gathers)
    auto prop = [&](const half1* feat, const half1* sub, const half1* add,
                    half1* outh, float* outf, int dim4, float scale,
                    int bnrelu, int used, const float* g, const float* bb,
                    const float* m, const float* v) {
        proph_kernel<<<divup(NN * dim4, 256), 256, 0, stream>>>(
            (const half4*)feat, (const half4*)sub, (const half4*)add,
            (half4*)outh, (f4*)outf, row_ptr, cw, NN, dim4, scale,
            sub != nullptr, bnrelu, used, g, bb, m, v);
    };

    // ---- layer 1 (din=128, dout=64, K=8) -> H1f ----
    gemm_mfma_kernel<<<NB, 512, 0, stream>>>(Xh, Wt1, bl[0], CB1h, NN);
    {
        auto C = [&](int k) { return (const half1*)(CB1h + (size_t)k * NN * 64); };
        prop1(C(7), nullptr, C(6), S0, nullptr, 2.f, 0, 0, 0, 0, 0);
        prop1(S0, C(7), C(5), S1, nullptr, 2.f, 0, 0, 0, 0, 0);
        prop1(S1, S0, C(4), S2, nullptr, 2.f, 0, 0, 0, 0, 0);
        prop1(S2, S1, C(3), S0, nullptr, 2.f, 0, 0, 0, 0, 0);
        prop1(S0, S2, C(2), S1, nullptr, 2.f, 0, 0, 0, 0, 0);
        prop1(S1, S0, C(1), S2, nullptr, 2.f, 0, 0, 0, 0, 0);
        prop1(S2, S1, C(0), nullptr, H1f, 1.f, 1,
              bn[0][0], bn[0][1], bn[0][2], bn[0][3]);
    }

    // ---- layer 2 (din=64, dout=18 pad 20, K=6): X=H1f -> H2f ----
    gemm_smallw_kernel<6, 16, 5><<<NB, 384, 0, stream>>>(H1f, Wp2, bl[1], 18,
                                                         (half4*)CBsh, NN);
    {
        auto C = [&](int k) { return (const half1*)(CBsh + (size_t)k * NN * 20); };
        prop(C(5), nullptr, C(4), S0, nullptr, 5, 2.f, 0, 18, 0, 0, 0, 0);
        prop(S0, C(5), C(3), S1, nullptr, 5, 2.f, 0, 18, 0, 0, 0, 0);
        prop(S1, S0, C(2), S2, nullptr, 5, 2.f, 0, 18, 0, 0, 0, 0);
        prop(S2, S1, C(1), S0, nullptr, 5, 2.f, 0, 18, 0, 0, 0, 0);
        prop(S0, S2, C(0), nullptr, H2f, 5, 1.f, 1, 18,
             bn[1][0], bn[1][1], bn[1][2], bn[1][3]);
    }

    // ---- layer 3 (din=18 str20, dout=9 pad 12, K=4): X=H2f -> H3f ----
    gemm_smallw_kernel<4, 5, 3><<<NB, 256, 0, stream>>>(H2f, Wp3, bl[2], 9,
                                                        (half4*)CBsh, NN);
    {
        auto C = [&](int k) { return (const half1*)(CBsh + (size_t)k * NN * 12); };
        prop(C(3), nullptr, C(2), S0, nullptr, 3, 2.f, 0, 9, 0, 0, 0, 0);
        prop(S0, C(3), C(1), S1, nullptr, 3, 2.f, 0, 9, 0, 0, 0, 0);
        prop(S1, S0, C(0), nullptr, H3f, 3, 1.f, 1, 9,
             bn[2][0], bn[2][1], bn[2][2], bn[2][3]);
    }

    // ---- layer 4 (din=9 str12, dout=10 pad 12, K=4): X=H3f -> d_out ----
    gemm_smallw_kernel<4, 3, 3><<<NB, 256, 0, stream>>>(H3f, Wp4, bl[3], 10,
                                                        (half4*)CBsh, NN);
    {
        auto C = [&](int k) { return (const half1*)(CBsh + (size_t)k * NN * 12); };
        prop(C(3), nullptr, C(2), S0, nullptr, 3, 2.f, 0, 10, 0, 0, 0, 0);
        prop(S0, C(3), C(1), S1, nullptr, 3, 2.f, 0, 10, 0, 0, 0, 0);
        propl_kernel<<<divup(NN * 3, 256), 256, 0, stream>>>(
            (const half4*)S1, (const half4*)S0, (const half4*)CBsh,
            (float*)d_out, row_ptr, cw, NN);
    }
}

// Round 9
// 788.540 us; speedup vs baseline: 1.4353x; 1.4353x over previous
//
#include <hip/hip_runtime.h>

#define NN 100000
#define NE 1600000
#define BN_EPS 1e-5f

// CSR binning parameters
#define BSH 7
#define BSZ (1 << BSH)   // 128 dsts per bucket
#define NBUCK 782        // divup(NN, BSZ)
#define NC 192           // edge chunks
#define CE 8334          // divup(NE, NC)

typedef _Float16 half1;
typedef _Float16 half4 __attribute__((ext_vector_type(4)));
typedef _Float16 h8 __attribute__((ext_vector_type(8)));
typedef float f4 __attribute__((ext_vector_type(4)));
typedef float f8 __attribute__((ext_vector_type(8)));

static inline int divup(int a, int b) { return (a + b - 1) / b; }

// per-edge source weight from packed entry: src in [0:17), deg_src in [17:32)
__device__ __forceinline__ float wsrc(unsigned int q) {
    unsigned int dg = q >> 17;
    return dg ? rsqrtf((float)dg) : 0.f;
}

// ---------------- preprocessing (no global atomics) ----------------

__global__ void histb_kernel(const int* __restrict__ dst, int* __restrict__ hist_g) {
    __shared__ int h[NBUCK];
    int c = blockIdx.x;
    for (int i = threadIdx.x; i < NBUCK; i += blockDim.x) h[i] = 0;
    __syncthreads();
    int e0 = c * CE, e1 = min(e0 + CE, NE);
    for (int e = e0 + threadIdx.x; e < e1; e += blockDim.x)
        atomicAdd(&h[dst[e] >> BSH], 1);
    __syncthreads();
    for (int i = threadIdx.x; i < NBUCK; i += blockDim.x) hist_g[c * NBUCK + i] = h[i];
}

__global__ void bscan1_kernel(const int* __restrict__ hist_g, int* __restrict__ bucket_start,
                              int* __restrict__ row_ptr) {
    __shared__ int sh[1024];
    int t = threadIdx.x;
    int tot = 0;
    if (t < NBUCK)
        for (int c = 0; c < NC; ++c) tot += hist_g[c * NBUCK + t];
    sh[t] = (t < NBUCK) ? tot : 0;
    __syncthreads();
    for (int off = 1; off < 1024; off <<= 1) {
        int v = (t >= off) ? sh[t - off] : 0;
        __syncthreads();
        sh[t] += v;
        __syncthreads();
    }
    if (t < NBUCK) bucket_start[t] = sh[t] - tot;
    if (t == 0) { bucket_start[NBUCK] = NE; row_ptr[NN] = NE; }
}

__global__ void boff_kernel(const int* __restrict__ bucket_start, const int* __restrict__ hist_g,
                            int* __restrict__ off_g) {
    int b = blockIdx.x * blockDim.x + threadIdx.x;
    if (b >= NBUCK) return;
    int run = bucket_start[b];
#pragma unroll 4
    for (int c = 0; c < NC; ++c) {
        off_g[c * NBUCK + b] = run;
        run += hist_g[c * NBUCK + b];
    }
}

__global__ void binscatter_kernel(const int* __restrict__ src, const int* __restrict__ dst,
                                  const int* __restrict__ off_g, unsigned int* __restrict__ tmp) {
    __shared__ int off_l[NBUCK];
    int myx = blockIdx.x & 7;
    int c = blockIdx.x >> 3;
    for (int i = threadIdx.x; i < NBUCK; i += blockDim.x)
        off_l[i] = ((i & 7) == myx) ? off_g[c * NBUCK + i] : 0;
    __syncthreads();
    int e0 = c * CE, e1 = min(e0 + CE, NE);
    for (int e = e0 + threadIdx.x; e < e1; e += blockDim.x) {
        int d = dst[e];
        int b = d >> BSH;
        if ((b & 7) != myx) continue;
        int s = src[e];
        int pos = atomicAdd(&off_l[b], 1);
        tmp[pos] = (unsigned int)s | ((unsigned int)(d & (BSZ - 1)) << 25);
    }
}

__global__ void finalize_kernel(const unsigned int* __restrict__ tmp,
                                const int* __restrict__ bucket_start,
                                int* __restrict__ row_ptr, int* __restrict__ deg,
                                unsigned int* __restrict__ cw) {
    __shared__ int cnt[BSZ], sc[BSZ], cur[BSZ];
    int b = blockIdx.x, t = threadIdx.x;
    int e0 = bucket_start[b], e1 = bucket_start[b + 1];
    if (t < BSZ) cnt[t] = 0;
    __syncthreads();
    for (int e = e0 + t; e < e1; e += blockDim.x) atomicAdd(&cnt[tmp[e] >> 25], 1);
    __syncthreads();
    if (t < BSZ) sc[t] = cnt[t];
    __syncthreads();
    for (int off = 1; off < BSZ; off <<= 1) {
        int v = (t >= off && t < BSZ) ? sc[t - off] : 0;
        __syncthreads();
        if (t < BSZ) sc[t] += v;
        __syncthreads();
    }
    if (t < BSZ) {
        int p = e0 + sc[t] - cnt[t];
        cur[t] = p;
        int nd = (b << BSH) + t;
        if (nd < NN) { row_ptr[nd] = p; deg[nd] = cnt[t]; }
    }
    __syncthreads();
    for (int e = e0 + t; e < e1; e += blockDim.x) {
        unsigned int r = tmp[e];
        int ld = r >> 25;
        int k = atomicAdd(&cur[ld], 1);
        cw[k] = r & 0x1FFFFu;
    }
}

__global__ void packdeg_kernel(unsigned int* __restrict__ cw, const int* __restrict__ deg) {
    int e = blockIdx.x * blockDim.x + threadIdx.x;
    if (e >= NE) return;
    unsigned int q = cw[e];
    int dg = deg[q];
    if (dg > 32767) dg = 32767;
    cw[e] = q | ((unsigned int)dg << 17);
}

// Wt[og][kd] = W1[og>>6][kd][og&63], fp16 ; Wt is [512][128]
__global__ void transw_kernel(const float* __restrict__ W, half1* __restrict__ Wt) {
    int i = blockIdx.x * blockDim.x + threadIdx.x;
    if (i >= 512 * 128) return;
    int kd = i >> 9;
    int og = i & 511;
    int k = og >> 6, o = og & 63;
    Wt[(size_t)og * 128 + kd] = (half1)W[((size_t)k * 128 + kd) * 64 + o];
}

// ---------------- W padding ----------------
__global__ void padw_kernel(const float* __restrict__ src, float* __restrict__ dst,
                            int K, int dins, int douts, int dind, int doutd) {
    int i = blockIdx.x * blockDim.x + threadIdx.x;
    int tot = K * dind * doutd;
    if (i >= tot) return;
    int o = i % doutd;
    int r = i / doutd;
    int dd = r % dind;
    int k = r / dind;
    dst[i] = (dd < dins && o < douts) ? src[((size_t)k * dins + dd) * douts + o] : 0.f;
}

// ---------------- Clenshaw prop, h8 (16B) gathers — dim == 64 ----------------
// 2 accumulators + unroll-4 staging: ~64-72 VGPR target for higher residency
// (R8 lesson: props are latency/MLP-bound -> resident-thread count is the lever).
__global__ void proph8_kernel(const h8* __restrict__ feat, const h8* __restrict__ sub,
                              const h8* __restrict__ add, h8* __restrict__ outh,
                              f8* __restrict__ outf,
                              const int* __restrict__ row_ptr, const unsigned int* __restrict__ cw,
                              int n, float scale, int has_sub, int bnrelu,
                              const float* __restrict__ bn_g, const float* __restrict__ bn_b,
                              const float* __restrict__ bn_m, const float* __restrict__ bn_v) {
    int idx = blockIdx.x * blockDim.x + threadIdx.x;
    if (idx >= n * 8) return;
    int nd = idx >> 3;
    int f = idx & 7;
    int e0 = row_ptr[nd], e1 = row_ptr[nd + 1];
    f8 a0 = {0.f, 0.f, 0.f, 0.f, 0.f, 0.f, 0.f, 0.f}, a1 = a0;
    int e = e0;
    for (; e + 4 <= e1; e += 4) {
        unsigned int q0 = cw[e], q1 = cw[e + 1], q2 = cw[e + 2], q3 = cw[e + 3];
        h8 h0 = feat[(size_t)(q0 & 0x1FFFFu) * 8 + f];
        h8 h1 = feat[(size_t)(q1 & 0x1FFFFu) * 8 + f];
        h8 h2 = feat[(size_t)(q2 & 0x1FFFFu) * 8 + f];
        h8 h3 = feat[(size_t)(q3 & 0x1FFFFu) * 8 + f];
        a0 += wsrc(q0) * __builtin_convertvector(h0, f8);
        a1 += wsrc(q1) * __builtin_convertvector(h1, f8);
        a0 += wsrc(q2) * __builtin_convertvector(h2, f8);
        a1 += wsrc(q3) * __builtin_convertvector(h3, f8);
    }
    for (; e < e1; ++e) {
        unsigned int q = cw[e];
        a0 += wsrc(q) * __builtin_convertvector(feat[(size_t)(q & 0x1FFFFu) * 8 + f], f8);
    }
    int degd = e1 - e0;
    float ms = (degd > 0) ? -scale * rsqrtf((float)degd) : 0.f;
    f8 r = (a0 + a1) * ms;
    if (has_sub) r -= __builtin_convertvector(sub[idx], f8);
    r += __builtin_convertvector(__builtin_nontemporal_load(&add[idx]), f8);
    if (bnrelu) {
#pragma unroll
        for (int c = 0; c < 8; ++c) {
            int o = f * 8 + c;
            float sc = bn_g[o] * rsqrtf(bn_v[o] + BN_EPS);
            r[c] = fmaxf(fmaf(r[c] - bn_m[o], sc, bn_b[o]), 0.f);
        }
    }
    if (outf) {
        outf[idx] = r;
    } else {
        outh[idx] = __builtin_convertvector(r, h8);
    }
}

// ---------------- Clenshaw prop, half4 gathers — small dims ----------------
__global__ void proph_kernel(const half4* __restrict__ feat, const half4* __restrict__ sub,
                             const half4* __restrict__ add, half4* __restrict__ outh,
                             f4* __restrict__ outf,
                             const int* __restrict__ row_ptr, const unsigned int* __restrict__ cw,
                             int n, int dim4, float scale, int has_sub,
                             int bnrelu, int used,
                             const float* __restrict__ bn_g, const float* __restrict__ bn_b,
                             const float* __restrict__ bn_m, const float* __restrict__ bn_v) {
    int idx = blockIdx.x * blockDim.x + threadIdx.x;
    if (idx >= n * dim4) return;
    int nd = idx / dim4;
    int f = idx - nd * dim4;
    int e0 = row_ptr[nd], e1 = row_ptr[nd + 1];
    f4 a0 = {0.f, 0.f, 0.f, 0.f}, a1 = a0, a2 = a0, a3 = a0;
    int e = e0;
    for (; e + 4 <= e1; e += 4) {
        unsigned int q0 = cw[e], q1 = cw[e + 1], q2 = cw[e + 2], q3 = cw[e + 3];
        f4 v0 = __builtin_convertvector(feat[(size_t)(q0 & 0x1FFFFu) * dim4 + f], f4);
        f4 v1 = __builtin_convertvector(feat[(size_t)(q1 & 0x1FFFFu) * dim4 + f], f4);
        f4 v2 = __builtin_convertvector(feat[(size_t)(q2 & 0x1FFFFu) * dim4 + f], f4);
        f4 v3 = __builtin_convertvector(feat[(size_t)(q3 & 0x1FFFFu) * dim4 + f], f4);
        a0 += wsrc(q0) * v0;
        a1 += wsrc(q1) * v1;
        a2 += wsrc(q2) * v2;
        a3 += wsrc(q3) * v3;
    }
    for (; e < e1; ++e) {
        unsigned int q = cw[e];
        a0 += wsrc(q) * __builtin_convertvector(feat[(size_t)(q & 0x1FFFFu) * dim4 + f], f4);
    }
    int degd = e1 - e0;
    float ms = (degd > 0) ? -scale * rsqrtf((float)degd) : 0.f;
    f4 r = ((a0 + a1) + (a2 + a3)) * ms;
    if (has_sub) r -= __builtin_convertvector(sub[idx], f4);
    r += __builtin_convertvector(__builtin_nontemporal_load(&add[idx]), f4);
    if (bnrelu) {
#pragma unroll
        for (int c = 0; c < 4; ++c) {
            int o = f * 4 + c;
            if (o < used) {
                float sc = bn_g[o] * rsqrtf(bn_v[o] + BN_EPS);
                r[c] = fmaxf(fmaf(r[c] - bn_m[o], sc, bn_b[o]), 0.f);
            } else r[c] = 0.f;
        }
    }
    if (outf) {
        outf[idx] = r;
    } else {
        half4 h;
        h.x = (half1)r.x; h.y = (half1)r.y; h.z = (half1)r.z; h.w = (half1)r.w;
        outh[idx] = h;
    }
}

// layer-4 final: fp16 gathers/streams at stride 12 (dim4=3), fp32 out at stride 10
__global__ void propl_kernel(const half4* __restrict__ feat, const half4* __restrict__ sub,
                             const half4* __restrict__ add, float* __restrict__ out,
                             const int* __restrict__ row_ptr, const unsigned int* __restrict__ cw,
                             int n) {
    int idx = blockIdx.x * blockDim.x + threadIdx.x;
    if (idx >= n * 3) return;
    int nd = idx / 3;
    int f = idx - nd * 3;
    int e0 = row_ptr[nd], e1 = row_ptr[nd + 1];
    f4 a0 = {0.f, 0.f, 0.f, 0.f}, a1 = a0, a2 = a0, a3 = a0;
    int e = e0;
    for (; e + 4 <= e1; e += 4) {
        unsigned int q0 = cw[e], q1 = cw[e + 1], q2 = cw[e + 2], q3 = cw[e + 3];
        a0 += wsrc(q0) * __builtin_convertvector(feat[(size_t)(q0 & 0x1FFFFu) * 3 + f], f4);
        a1 += wsrc(q1) * __builtin_convertvector(feat[(size_t)(q1 & 0x1FFFFu) * 3 + f], f4);
        a2 += wsrc(q2) * __builtin_convertvector(feat[(size_t)(q2 & 0x1FFFFu) * 3 + f], f4);
        a3 += wsrc(q3) * __builtin_convertvector(feat[(size_t)(q3 & 0x1FFFFu) * 3 + f], f4);
    }
    for (; e < e1; ++e) {
        unsigned int q = cw[e];
        a0 += wsrc(q) * __builtin_convertvector(feat[(size_t)(q & 0x1FFFFu) * 3 + f], f4);
    }
    int degd = e1 - e0;
    float ms = (degd > 0) ? -rsqrtf((float)degd) : 0.f;
    f4 r = ((a0 + a1) + (a2 + a3)) * ms;
    r -= __builtin_convertvector(sub[idx], f4);
    r += __builtin_convertvector(add[idx], f4);
    int o = f * 4;
    float* orow = out + (size_t)nd * 10;
    if (o + 0 < 10) orow[o + 0] = r.x;
    if (o + 1 < 10) orow[o + 1] = r.y;
    if (o + 2 < 10) orow[o + 2] = r.z;
    if (o + 3 < 10) orow[o + 3] = r.w;
}

// ---------------- layer-1 GEMM via MFMA (8 waves = 8 k-slices, 64-node tile) --------
// R5 structure (73us, 0 conflicts); reads fp32 X directly (cvtx fused: in-register
// f32->f16 convert — VALU was 5% busy, free), row-major CB epilogue via LDS slab.
#define LSTR 68
__global__ __launch_bounds__(512) void gemm_mfma_kernel(
        const float* __restrict__ X, const half1* __restrict__ Wt,
        const float* __restrict__ bias, half1* __restrict__ CB, int n) {
    __shared__ half1 lds[8 * 32 * LSTR];  // 34816 B
    int lane = threadIdx.x & 63;
    int ks = threadIdx.x >> 6;   // 0..7
    int m16 = lane & 15;
    int quad = lane >> 4;
    int ntile = blockIdx.x * 64;

    f4 acc[4][4];
#pragma unroll
    for (int nt = 0; nt < 4; ++nt)
#pragma unroll
        for (int i = 0; i < 4; ++i) acc[nt][i] = (f4){0.f, 0.f, 0.f, 0.f};

#pragma unroll
    for (int kc = 0; kc < 4; ++kc) {
        int koff = kc * 32 + quad * 8;
        h8 a[4];
#pragma unroll
        for (int i = 0; i < 4; ++i)
            a[i] = *(const h8*)(Wt + (size_t)(ks * 64 + i * 16 + m16) * 128 + koff);
        h8 b[4];
#pragma unroll
        for (int nt = 0; nt < 4; ++nt) {
            int node = min(ntile + nt * 16 + m16, n - 1);
            const float* xr = X + (size_t)node * 128 + koff;
            f4 lo = *(const f4*)xr;
            f4 hi = *(const f4*)(xr + 4);
            h8 bb;
#pragma unroll
            for (int c = 0; c < 4; ++c) { bb[c] = (half1)lo[c]; bb[c + 4] = (half1)hi[c]; }
            b[nt] = bb;
        }
#pragma unroll
        for (int nt = 0; nt < 4; ++nt)
#pragma unroll
            for (int i = 0; i < 4; ++i)
                acc[nt][i] = __builtin_amdgcn_mfma_f32_16x16x32_f16(a[i], b[nt], acc[nt][i], 0, 0, 0);
    }

    half1* slab = lds + (size_t)ks * 32 * LSTR;
    int nl0 = lane >> 3;    // 0..7
    int chunk = lane & 7;   // 0..7, 16B each
#pragma unroll
    for (int hh = 0; hh < 2; ++hh) {
        // stage 32 nodes (nt = 2*hh, 2*hh+1) into this wave's slab
#pragma unroll
        for (int p = 0; p < 2; ++p) {
            int nt = hh * 2 + p;
            int node_l = p * 16 + m16;
#pragma unroll
            for (int i = 0; i < 4; ++i) {
                int ob = i * 16 + quad * 4;
                f4 v = acc[nt][i];
                if (ks == 0) {
                    const f4 b4 = *(const f4*)(bias + ob);
                    v += b4;
                }
                half4 h;
                h.x = (half1)v[0]; h.y = (half1)v[1]; h.z = (half1)v[2]; h.w = (half1)v[3];
                *(half4*)(slab + node_l * LSTR + ob) = h;
            }
        }
        asm volatile("s_waitcnt lgkmcnt(0)" ::: "memory");  // cross-lane RAW within wave
        // coalesced copy-out: 8 lanes per 128B node row
#pragma unroll
        for (int j = 0; j < 4; ++j) {
            int node_l = j * 8 + nl0;
            int node = ntile + hh * 32 + node_l;
            if (node < n) {
                h8 v = *(const h8*)(slab + node_l * LSTR + chunk * 8);
                *(h8*)(CB + ((size_t)ks * n + node) * 64 + chunk * 8) = v;
            }
        }
        // DS ops in-order per wave: hh=1 restage cannot pass the reads above.
    }
}

// ---------------- small-layer GEMM: block = KK waves, wave k, lane = node -------------
template <int KK, int DIN4, int NACC>
__global__ void gemm_smallw_kernel(const float* __restrict__ X, const float* __restrict__ Wp,
                                   const float* __restrict__ bias, int dout,
                                   half4* __restrict__ CB, int n) {
    int lane = threadIdx.x & 63;
    int k = __builtin_amdgcn_readfirstlane((int)(threadIdx.x >> 6));
    int node0 = blockIdx.x * 64 + lane;
    int node = min(node0, n - 1);
    f4 acc[NACC];
#pragma unroll
    for (int i = 0; i < NACC; ++i) {
        f4 v = {0.f, 0.f, 0.f, 0.f};
        if (k == 0 && bias) {
#pragma unroll
            for (int c = 0; c < 4; ++c) {
                int o = i * 4 + c;
                v[c] = (o < dout) ? bias[o] : 0.f;
            }
        }
        acc[i] = v;
    }
    const f4* Xr = (const f4*)(X + (size_t)node * (DIN4 * 4));
    const f4* Wk = (const f4*)(Wp + (size_t)k * (DIN4 * 4) * (NACC * 4));
    for (int d4 = 0; d4 < DIN4; ++d4) {
        f4 xv = Xr[d4];
#pragma unroll
        for (int j = 0; j < 4; ++j) {
            float xs = xv[j];
#pragma unroll
            for (int i = 0; i < NACC; ++i)
                acc[i] += xs * Wk[(d4 * 4 + j) * NACC + i];
        }
    }
    if (node0 < n) {
        size_t base = ((size_t)k * n + node) * NACC;
#pragma unroll
        for (int i = 0; i < NACC; ++i) {
            half4 h;
            h.x = (half1)acc[i].x; h.y = (half1)acc[i].y;
            h.z = (half1)acc[i].z; h.w = (half1)acc[i].w;
            CB[base + i] = h;
        }
    }
}

// ---------------- host driver ----------------

extern "C" void kernel_launch(void* const* d_in, const int* in_sizes, int n_in,
                              void* d_out, int out_size, void* d_ws, size_t ws_size,
                              hipStream_t stream) {
    const float* x  = (const float*)d_in[0];
    const int*   ei = (const int*)d_in[1];
    const float* Wl[4] = {(const float*)d_in[2], (const float*)d_in[4],
                          (const float*)d_in[6], (const float*)d_in[8]};
    const float* bl[4] = {(const float*)d_in[3], (const float*)d_in[5],
                          (const float*)d_in[7], (const float*)d_in[9]};
    const float* bn[3][4];
    for (int l = 0; l < 3; ++l)
        for (int j = 0; j < 4; ++j)
            bn[l][j] = (const float*)d_in[10 + 4 * l + j];

    char* ws = (char*)d_ws;
    size_t off = 0;
    auto alloc = [&](size_t bytes) -> void* {
        void* p = (void*)(ws + off);
        off = (off + bytes + 255) & ~(size_t)255;
        return p;
    };
    int*   deg      = (int*)alloc(NN * 4);
    int*   row_ptr  = (int*)alloc((NN + 1) * 4);
    int*   bstart   = (int*)alloc((NBUCK + 1) * 4);
    unsigned int* cw = (unsigned int*)alloc((size_t)NE * 4);
    half1* CB1h    = (half1*)alloc((size_t)8 * NN * 64 * 2);
    half1* CBsh    = (half1*)alloc((size_t)6 * NN * 20 * 2);
    half1* S0      = (half1*)alloc((size_t)NN * 64 * 2);
    half1* S1      = (half1*)alloc((size_t)NN * 64 * 2);
    half1* S2      = (half1*)alloc((size_t)NN * 64 * 2);
    float* H1f     = (float*)alloc((size_t)NN * 64 * 4);
    float* H2f     = (float*)alloc((size_t)NN * 20 * 4);
    float* H3f     = (float*)alloc((size_t)NN * 12 * 4);
    float* Wp2     = (float*)alloc((size_t)6 * 64 * 20 * 4);
    float* Wp3     = (float*)alloc((size_t)4 * 20 * 12 * 4);
    float* Wp4     = (float*)alloc((size_t)4 * 12 * 12 * 4);
    half1* Wt1     = (half1*)alloc((size_t)512 * 128 * 2);

    // CSR-build scratch aliased into CB1h (consumed before gemm_mfma writes it):
    unsigned int* tmp = (unsigned int*)CB1h;                // 6.4 MB
    int* hist_g = (int*)((char*)CB1h + (16u << 20));        // NC*NBUCK*4 = 600 KB
    int* off_g  = hist_g + NC * NBUCK;                      // 600 KB

    const int* srcp = ei;
    const int* dstp = ei + NE;
    const int NB = divup(NN, 64);

    histb_kernel<<<NC, 256, 0, stream>>>(dstp, hist_g);
    bscan1_kernel<<<1, 1024, 0, stream>>>(hist_g, bstart, row_ptr);
    boff_kernel<<<divup(NBUCK, 256), 256, 0, stream>>>(bstart, hist_g, off_g);
    binscatter_kernel<<<NC * 8, 256, 0, stream>>>(srcp, dstp, off_g, tmp);
    finalize_kernel<<<NBUCK, 256, 0, stream>>>(tmp, bstart, row_ptr, deg, cw);
    packdeg_kernel<<<divup(NE, 256), 256, 0, stream>>>(cw, deg);

    transw_kernel<<<divup(512 * 128, 256), 256, 0, stream>>>(Wl[0], Wt1);
    padw_kernel<<<divup(6 * 64 * 20, 256), 256, 0, stream>>>(Wl[1], Wp2, 6, 64, 18, 64, 20);
    padw_kernel<<<divup(4 * 20 * 12, 256), 256, 0, stream>>>(Wl[2], Wp3, 4, 18, 9, 20, 12);
    padw_kernel<<<divup(4 * 12 * 12, 256), 256, 0, stream>>>(Wl[3], Wp4, 4, 9, 10, 12, 12);

    // dim-64 prop (h8 gathers)
    auto prop1 = [&](const half1* feat, const half1* sub, const half1* add,
                     half1* outh, float* outf, float scale, int bnrelu,
                     const float* g, const float* bb, const float* m, const float* v) {
        proph8_kernel<<<divup(NN * 8, 256), 256, 0, stream>>>(
            (const h8*)feat, (const h8*)sub, (const h8*)add,
            (h8*)outh, (f8*)outf, row_ptr, cw, NN, scale,
            sub != nullptr, bnrelu, g, bb, m, v);
    };
    // small-dim prop (half4 gathers)
    auto prop = [&](const half1* feat, const half1* sub, const half1* add,
                    half1* outh, float* outf, int dim4, float scale,
                    int bnrelu, int used, const float* g, const float* bb,
                    const float* m, const float* v) {
        proph_kernel<<<divup(NN * dim4, 256), 256, 0, stream>>>(
            (const half4*)feat, (const half4*)sub, (const half4*)add,
            (half4*)outh, (f4*)outf, row_ptr, cw, NN, dim4, scale,
            sub != nullptr, bnrelu, used, g, bb, m, v);
    };

    // ---- layer 1 (din=128, dout=64, K=8) -> H1f ----
    gemm_mfma_kernel<<<NB, 512, 0, stream>>>(x, Wt1, bl[0], CB1h, NN);
    {
        auto C = [&](int k) { return (const half1*)(CB1h + (size_t)k * NN * 64); };
        prop1(C(7), nullptr, C(6), S0, nullptr, 2.f, 0, 0, 0, 0, 0);
        prop1(S0, C(7), C(5), S1, nullptr, 2.f, 0, 0, 0, 0, 0);
        prop1(S1, S0, C(4), S2, nullptr, 2.f, 0, 0, 0, 0, 0);
        prop1(S2, S1, C(3), S0, nullptr, 2.f, 0, 0, 0, 0, 0);
        prop1(S0, S2, C(2), S1, nullptr, 2.f, 0, 0, 0, 0, 0);
        prop1(S1, S0, C(1), S2, nullptr, 2.f, 0, 0, 0, 0, 0);
        prop1(S2, S1, C(0), nullptr, H1f, 1.f, 1,
              bn[0][0], bn[0][1], bn[0][2], bn[0][3]);
    }

    // ---- layer 2 (din=64, dout=18 pad 20, K=6): X=H1f -> H2f ----
    gemm_smallw_kernel<6, 16, 5><<<NB, 384, 0, stream>>>(H1f, Wp2, bl[1], 18,
                                                         (half4*)CBsh, NN);
    {
        auto C = [&](int k) { return (const half1*)(CBsh + (size_t)k * NN * 20); };
        prop(C(5), nullptr, C(4), S0, nullptr, 5, 2.f, 0, 18, 0, 0, 0, 0);
        prop(S0, C(5), C(3), S1, nullptr, 5, 2.f, 0, 18, 0, 0, 0, 0);
        prop(S1, S0, C(2), S2, nullptr, 5, 2.f, 0, 18, 0, 0, 0, 0);
        prop(S2, S1, C(1), S0, nullptr, 5, 2.f, 0, 18, 0, 0, 0, 0);
        prop(S0, S2, C(0), nullptr, H2f, 5, 1.f, 1, 18,
             bn[1][0], bn[1][1], bn[1][2], bn[1][3]);
    }

    // ---- layer 3 (din=18 str20, dout=9 pad 12, K=4): X=H2f -> H3f ----
    gemm_smallw_kernel<4, 5, 3><<<NB, 256, 0, stream>>>(H2f, Wp3, bl[2], 9,
                                                        (half4*)CBsh, NN);
    {
        auto C = [&](int k) { return (const half1*)(CBsh + (size_t)k * NN * 12); };
        prop(C(3), nullptr, C(2), S0, nullptr, 3, 2.f, 0, 9, 0, 0, 0, 0);
        prop(S0, C(3), C(1), S1, nullptr, 3, 2.f, 0, 9, 0, 0, 0, 0);
        prop(S1, S0, C(0), nullptr, H3f, 3, 1.f, 1, 9,
             bn[2][0], bn[2][1], bn[2][2], bn[2][3]);
    }

    // ---- layer 4 (din=9 str12, dout=10 pad 12, K=4): X=H3f -> d_out ----
    gemm_smallw_kernel<4, 3, 3><<<NB, 256, 0, stream>>>(H3f, Wp4, bl[3], 10,
                                                        (half4*)CBsh, NN);
    {
        auto C = [&](int k) { return (const half1*)(CBsh + (size_t)k * NN * 12); };
        prop(C(3), nullptr, C(2), S0, nullptr, 3, 2.f, 0, 10, 0, 0, 0, 0);
        prop(S0, C(3), C(1), S1, nullptr, 3, 2.f, 0, 10, 0, 0, 0, 0);
        propl_kernel<<<divup(NN * 3, 256), 256, 0, stream>>>(
            (const half4*)S1, (const half4*)S0, (const half4*)CBsh,
            (float*)d_out, row_ptr, cw, NN);
    }
}

// Round 10
// 787.273 us; speedup vs baseline: 1.4376x; 1.0016x over previous
//
#include <hip/hip_runtime.h>

#define NN 100000
#define NE 1600000
#define BN_EPS 1e-5f

// CSR binning parameters
#define BSH 7
#define BSZ (1 << BSH)   // 128 dsts per bucket
#define NBUCK 782        // divup(NN, BSZ)
#define NC 192           // edge chunks
#define CE 8334          // divup(NE, NC)

typedef _Float16 half1;
typedef _Float16 half4 __attribute__((ext_vector_type(4)));
typedef _Float16 h8 __attribute__((ext_vector_type(8)));
typedef float f4 __attribute__((ext_vector_type(4)));
typedef float f8 __attribute__((ext_vector_type(8)));

static inline int divup(int a, int b) { return (a + b - 1) / b; }

// per-edge source weight from packed entry: src in [0:17), deg_src in [17:32)
__device__ __forceinline__ float wsrc(unsigned int q) {
    unsigned int dg = q >> 17;
    return dg ? rsqrtf((float)dg) : 0.f;
}

// ---------------- preprocessing (no global atomics) ----------------

__global__ void histb_kernel(const int* __restrict__ dst, int* __restrict__ hist_g) {
    __shared__ int h[NBUCK];
    int c = blockIdx.x;
    for (int i = threadIdx.x; i < NBUCK; i += blockDim.x) h[i] = 0;
    __syncthreads();
    int e0 = c * CE, e1 = min(e0 + CE, NE);
    for (int e = e0 + threadIdx.x; e < e1; e += blockDim.x)
        atomicAdd(&h[dst[e] >> BSH], 1);
    __syncthreads();
    for (int i = threadIdx.x; i < NBUCK; i += blockDim.x) hist_g[c * NBUCK + i] = h[i];
}

__global__ void bscan1_kernel(const int* __restrict__ hist_g, int* __restrict__ bucket_start,
                              int* __restrict__ row_ptr) {
    __shared__ int sh[1024];
    int t = threadIdx.x;
    int tot = 0;
    if (t < NBUCK)
        for (int c = 0; c < NC; ++c) tot += hist_g[c * NBUCK + t];
    sh[t] = (t < NBUCK) ? tot : 0;
    __syncthreads();
    for (int off = 1; off < 1024; off <<= 1) {
        int v = (t >= off) ? sh[t - off] : 0;
        __syncthreads();
        sh[t] += v;
        __syncthreads();
    }
    if (t < NBUCK) bucket_start[t] = sh[t] - tot;
    if (t == 0) { bucket_start[NBUCK] = NE; row_ptr[NN] = NE; }
}

__global__ void boff_kernel(const int* __restrict__ bucket_start, const int* __restrict__ hist_g,
                            int* __restrict__ off_g) {
    int b = blockIdx.x * blockDim.x + threadIdx.x;
    if (b >= NBUCK) return;
    int run = bucket_start[b];
#pragma unroll 4
    for (int c = 0; c < NC; ++c) {
        off_g[c * NBUCK + b] = run;
        run += hist_g[c * NBUCK + b];
    }
}

__global__ void binscatter_kernel(const int* __restrict__ src, const int* __restrict__ dst,
                                  const int* __restrict__ off_g, unsigned int* __restrict__ tmp) {
    __shared__ int off_l[NBUCK];
    int myx = blockIdx.x & 7;
    int c = blockIdx.x >> 3;
    for (int i = threadIdx.x; i < NBUCK; i += blockDim.x)
        off_l[i] = ((i & 7) == myx) ? off_g[c * NBUCK + i] : 0;
    __syncthreads();
    int e0 = c * CE, e1 = min(e0 + CE, NE);
    for (int e = e0 + threadIdx.x; e < e1; e += blockDim.x) {
        int d = dst[e];
        int b = d >> BSH;
        if ((b & 7) != myx) continue;
        int s = src[e];
        int pos = atomicAdd(&off_l[b], 1);
        tmp[pos] = (unsigned int)s | ((unsigned int)(d & (BSZ - 1)) << 25);
    }
}

__global__ void finalize_kernel(const unsigned int* __restrict__ tmp,
                                const int* __restrict__ bucket_start,
                                int* __restrict__ row_ptr, int* __restrict__ deg,
                                unsigned int* __restrict__ cw) {
    __shared__ int cnt[BSZ], sc[BSZ], cur[BSZ];
    int b = blockIdx.x, t = threadIdx.x;
    int e0 = bucket_start[b], e1 = bucket_start[b + 1];
    if (t < BSZ) cnt[t] = 0;
    __syncthreads();
    for (int e = e0 + t; e < e1; e += blockDim.x) atomicAdd(&cnt[tmp[e] >> 25], 1);
    __syncthreads();
    if (t < BSZ) sc[t] = cnt[t];
    __syncthreads();
    for (int off = 1; off < BSZ; off <<= 1) {
        int v = (t >= off && t < BSZ) ? sc[t - off] : 0;
        __syncthreads();
        if (t < BSZ) sc[t] += v;
        __syncthreads();
    }
    if (t < BSZ) {
        int p = e0 + sc[t] - cnt[t];
        cur[t] = p;
        int nd = (b << BSH) + t;
        if (nd < NN) { row_ptr[nd] = p; deg[nd] = cnt[t]; }
    }
    __syncthreads();
    for (int e = e0 + t; e < e1; e += blockDim.x) {
        unsigned int r = tmp[e];
        int ld = r >> 25;
        int k = atomicAdd(&cur[ld], 1);
        cw[k] = r & 0x1FFFFu;
    }
}

__global__ void packdeg_kernel(unsigned int* __restrict__ cw, const int* __restrict__ deg) {
    int e = blockIdx.x * blockDim.x + threadIdx.x;
    if (e >= NE) return;
    unsigned int q = cw[e];
    int dg = deg[q];
    if (dg > 32767) dg = 32767;
    cw[e] = q | ((unsigned int)dg << 17);
}

// ---------------- fp16 converts for MFMA ----------------

__global__ void cvtx_kernel(const float4* __restrict__ X, half4* __restrict__ Xh, int tot4) {
    int i = blockIdx.x * blockDim.x + threadIdx.x;
    if (i >= tot4) return;
    float4 v = X[i];
    half4 h;
    h.x = (half1)v.x; h.y = (half1)v.y; h.z = (half1)v.z; h.w = (half1)v.w;
    Xh[i] = h;
}

// Wt[og][kd] = W1[og>>6][kd][og&63], fp16 ; Wt is [512][128]
__global__ void transw_kernel(const float* __restrict__ W, half1* __restrict__ Wt) {
    int i = blockIdx.x * blockDim.x + threadIdx.x;
    if (i >= 512 * 128) return;
    int kd = i >> 9;
    int og = i & 511;
    int k = og >> 6, o = og & 63;
    Wt[(size_t)og * 128 + kd] = (half1)W[((size_t)k * 128 + kd) * 64 + o];
}

// ---------------- W padding ----------------
__global__ void padw_kernel(const float* __restrict__ src, float* __restrict__ dst,
                            int K, int dins, int douts, int dind, int doutd) {
    int i = blockIdx.x * blockDim.x + threadIdx.x;
    int tot = K * dind * doutd;
    if (i >= tot) return;
    int o = i % doutd;
    int r = i / doutd;
    int dd = r % dind;
    int k = r / dind;
    dst[i] = (dd < dins && o < douts) ? src[((size_t)k * dins + dd) * douts + o] : 0.f;
}

// ---------------- Clenshaw prop, h8 (16B) gathers — dim == 64 ----------------
// 2 accumulators (R9 win: higher residency, props are latency-bound);
// cw loaded as aligned uint4 (scalar prologue aligns e to 4).
__global__ void proph8_kernel(const h8* __restrict__ feat, const h8* __restrict__ sub,
                              const h8* __restrict__ add, h8* __restrict__ outh,
                              f8* __restrict__ outf,
                              const int* __restrict__ row_ptr, const unsigned int* __restrict__ cw,
                              int n, float scale, int has_sub, int bnrelu,
                              const float* __restrict__ bn_g, const float* __restrict__ bn_b,
                              const float* __restrict__ bn_m, const float* __restrict__ bn_v) {
    int idx = blockIdx.x * blockDim.x + threadIdx.x;
    if (idx >= n * 8) return;
    int nd = idx >> 3;
    int f = idx & 7;
    int e0 = row_ptr[nd], e1 = row_ptr[nd + 1];
    f8 a0 = {0.f, 0.f, 0.f, 0.f, 0.f, 0.f, 0.f, 0.f}, a1 = a0;
    int e = e0;
    int pre = (4 - (e0 & 3)) & 3;
    if (pre > e1 - e0) pre = e1 - e0;
    for (int p = 0; p < pre; ++p, ++e) {
        unsigned int q = cw[e];
        a0 += wsrc(q) * __builtin_convertvector(feat[(size_t)(q & 0x1FFFFu) * 8 + f], f8);
    }
    for (; e + 4 <= e1; e += 4) {
        uint4 qv = *(const uint4*)&cw[e];   // 16B-aligned (e%4==0, cw 256B-aligned)
        h8 h0 = feat[(size_t)(qv.x & 0x1FFFFu) * 8 + f];
        h8 h1 = feat[(size_t)(qv.y & 0x1FFFFu) * 8 + f];
        h8 h2 = feat[(size_t)(qv.z & 0x1FFFFu) * 8 + f];
        h8 h3 = feat[(size_t)(qv.w & 0x1FFFFu) * 8 + f];
        a0 += wsrc(qv.x) * __builtin_convertvector(h0, f8);
        a1 += wsrc(qv.y) * __builtin_convertvector(h1, f8);
        a0 += wsrc(qv.z) * __builtin_convertvector(h2, f8);
        a1 += wsrc(qv.w) * __builtin_convertvector(h3, f8);
    }
    for (; e < e1; ++e) {
        unsigned int q = cw[e];
        a0 += wsrc(q) * __builtin_convertvector(feat[(size_t)(q & 0x1FFFFu) * 8 + f], f8);
    }
    int degd = e1 - e0;
    float ms = (degd > 0) ? -scale * rsqrtf((float)degd) : 0.f;
    f8 r = (a0 + a1) * ms;
    if (has_sub) r -= __builtin_convertvector(sub[idx], f8);
    r += __builtin_convertvector(__builtin_nontemporal_load(&add[idx]), f8);
    if (bnrelu) {
#pragma unroll
        for (int c = 0; c < 8; ++c) {
            int o = f * 8 + c;
            float sc = bn_g[o] * rsqrtf(bn_v[o] + BN_EPS);
            r[c] = fmaxf(fmaf(r[c] - bn_m[o], sc, bn_b[o]), 0.f);
        }
    }
    if (outf) {
        outf[idx] = r;
    } else {
        outh[idx] = __builtin_convertvector(r, h8);
    }
}

// ---------------- Clenshaw prop, half4 gathers — small dims ----------------
__global__ void proph_kernel(const half4* __restrict__ feat, const half4* __restrict__ sub,
                             const half4* __restrict__ add, half4* __restrict__ outh,
                             f4* __restrict__ outf,
                             const int* __restrict__ row_ptr, const unsigned int* __restrict__ cw,
                             int n, int dim4, float scale, int has_sub,
                             int bnrelu, int used,
                             const float* __restrict__ bn_g, const float* __restrict__ bn_b,
                             const float* __restrict__ bn_m, const float* __restrict__ bn_v) {
    int idx = blockIdx.x * blockDim.x + threadIdx.x;
    if (idx >= n * dim4) return;
    int nd = idx / dim4;
    int f = idx - nd * dim4;
    int e0 = row_ptr[nd], e1 = row_ptr[nd + 1];
    f4 a0 = {0.f, 0.f, 0.f, 0.f}, a1 = a0, a2 = a0, a3 = a0;
    int e = e0;
    for (; e + 4 <= e1; e += 4) {
        unsigned int q0 = cw[e], q1 = cw[e + 1], q2 = cw[e + 2], q3 = cw[e + 3];
        f4 v0 = __builtin_convertvector(feat[(size_t)(q0 & 0x1FFFFu) * dim4 + f], f4);
        f4 v1 = __builtin_convertvector(feat[(size_t)(q1 & 0x1FFFFu) * dim4 + f], f4);
        f4 v2 = __builtin_convertvector(feat[(size_t)(q2 & 0x1FFFFu) * dim4 + f], f4);
        f4 v3 = __builtin_convertvector(feat[(size_t)(q3 & 0x1FFFFu) * dim4 + f], f4);
        a0 += wsrc(q0) * v0;
        a1 += wsrc(q1) * v1;
        a2 += wsrc(q2) * v2;
        a3 += wsrc(q3) * v3;
    }
    for (; e < e1; ++e) {
        unsigned int q = cw[e];
        a0 += wsrc(q) * __builtin_convertvector(feat[(size_t)(q & 0x1FFFFu) * dim4 + f], f4);
    }
    int degd = e1 - e0;
    float ms = (degd > 0) ? -scale * rsqrtf((float)degd) : 0.f;
    f4 r = ((a0 + a1) + (a2 + a3)) * ms;
    if (has_sub) r -= __builtin_convertvector(sub[idx], f4);
    r += __builtin_convertvector(__builtin_nontemporal_load(&add[idx]), f4);
    if (bnrelu) {
#pragma unroll
        for (int c = 0; c < 4; ++c) {
            int o = f * 4 + c;
            if (o < used) {
                float sc = bn_g[o] * rsqrtf(bn_v[o] + BN_EPS);
                r[c] = fmaxf(fmaf(r[c] - bn_m[o], sc, bn_b[o]), 0.f);
            } else r[c] = 0.f;
        }
    }
    if (outf) {
        outf[idx] = r;
    } else {
        half4 h;
        h.x = (half1)r.x; h.y = (half1)r.y; h.z = (half1)r.z; h.w = (half1)r.w;
        outh[idx] = h;
    }
}

// layer-4 final: fp16 gathers/streams at stride 12 (dim4=3), fp32 out at stride 10
__global__ void propl_kernel(const half4* __restrict__ feat, const half4* __restrict__ sub,
                             const half4* __restrict__ add, float* __restrict__ out,
                             const int* __restrict__ row_ptr, const unsigned int* __restrict__ cw,
                             int n) {
    int idx = blockIdx.x * blockDim.x + threadIdx.x;
    if (idx >= n * 3) return;
    int nd = idx / 3;
    int f = idx - nd * 3;
    int e0 = row_ptr[nd], e1 = row_ptr[nd + 1];
    f4 a0 = {0.f, 0.f, 0.f, 0.f}, a1 = a0, a2 = a0, a3 = a0;
    int e = e0;
    for (; e + 4 <= e1; e += 4) {
        unsigned int q0 = cw[e], q1 = cw[e + 1], q2 = cw[e + 2], q3 = cw[e + 3];
        a0 += wsrc(q0) * __builtin_convertvector(feat[(size_t)(q0 & 0x1FFFFu) * 3 + f], f4);
        a1 += wsrc(q1) * __builtin_convertvector(feat[(size_t)(q1 & 0x1FFFFu) * 3 + f], f4);
        a2 += wsrc(q2) * __builtin_convertvector(feat[(size_t)(q2 & 0x1FFFFu) * 3 + f], f4);
        a3 += wsrc(q3) * __builtin_convertvector(feat[(size_t)(q3 & 0x1FFFFu) * 3 + f], f4);
    }
    for (; e < e1; ++e) {
        unsigned int q = cw[e];
        a0 += wsrc(q) * __builtin_convertvector(feat[(size_t)(q & 0x1FFFFu) * 3 + f], f4);
    }
    int degd = e1 - e0;
    float ms = (degd > 0) ? -rsqrtf((float)degd) : 0.f;
    f4 r = ((a0 + a1) + (a2 + a3)) * ms;
    r -= __builtin_convertvector(sub[idx], f4);
    r += __builtin_convertvector(add[idx], f4);
    int o = f * 4;
    float* orow = out + (size_t)nd * 10;
    if (o + 0 < 10) orow[o + 0] = r.x;
    if (o + 1 < 10) orow[o + 1] = r.y;
    if (o + 2 < 10) orow[o + 2] = r.z;
    if (o + 3 < 10) orow[o + 3] = r.w;
}

// ---------------- layer-1 GEMM via MFMA (8 waves = 8 k-slices, 64-node tile) --------
// R5 structure restored (73us, 0 conflicts): fp16 Xh input, per-wave LDS slab,
// no barriers, LSTR=68.
#define LSTR 68
__global__ __launch_bounds__(512) void gemm_mfma_kernel(
        const half1* __restrict__ Xh, const half1* __restrict__ Wt,
        const float* __restrict__ bias, half1* __restrict__ CB, int n) {
    __shared__ half1 lds[8 * 32 * LSTR];  // 34816 B
    int lane = threadIdx.x & 63;
    int ks = threadIdx.x >> 6;   // 0..7
    int m16 = lane & 15;
    int quad = lane >> 4;
    int ntile = blockIdx.x * 64;

    f4 acc[4][4];
#pragma unroll
    for (int nt = 0; nt < 4; ++nt)
#pragma unroll
        for (int i = 0; i < 4; ++i) acc[nt][i] = (f4){0.f, 0.f, 0.f, 0.f};

#pragma unroll
    for (int kc = 0; kc < 4; ++kc) {
        int koff = kc * 32 + quad * 8;
        h8 a[4];
#pragma unroll
        for (int i = 0; i < 4; ++i)
            a[i] = *(const h8*)(Wt + (size_t)(ks * 64 + i * 16 + m16) * 128 + koff);
        h8 b[4];
#pragma unroll
        for (int nt = 0; nt < 4; ++nt) {
            int node = min(ntile + nt * 16 + m16, n - 1);
            b[nt] = *(const h8*)(Xh + (size_t)node * 128 + koff);
        }
#pragma unroll
        for (int nt = 0; nt < 4; ++nt)
#pragma unroll
            for (int i = 0; i < 4; ++i)
                acc[nt][i] = __builtin_amdgcn_mfma_f32_16x16x32_f16(a[i], b[nt], acc[nt][i], 0, 0, 0);
    }

    half1* slab = lds + (size_t)ks * 32 * LSTR;
    int nl0 = lane >> 3;    // 0..7
    int chunk = lane & 7;   // 0..7, 16B each
#pragma unroll
    for (int hh = 0; hh < 2; ++hh) {
        // stage 32 nodes (nt = 2*hh, 2*hh+1) into this wave's slab
#pragma unroll
        for (int p = 0; p < 2; ++p) {
            int nt = hh * 2 + p;
            int node_l = p * 16 + m16;
#pragma unroll
            for (int i = 0; i < 4; ++i) {
                int ob = i * 16 + quad * 4;
                f4 v = acc[nt][i];
                if (ks == 0) {
                    const f4 b4 = *(const f4*)(bias + ob);
                    v += b4;
                }
                half4 h;
                h.x = (half1)v[0]; h.y = (half1)v[1]; h.z = (half1)v[2]; h.w = (half1)v[3];
                *(half4*)(slab + node_l * LSTR + ob) = h;
            }
        }
        asm volatile("s_waitcnt lgkmcnt(0)" ::: "memory");  // cross-lane RAW within wave
        // coalesced copy-out: 8 lanes per 128B node row
#pragma unroll
        for (int j = 0; j < 4; ++j) {
            int node_l = j * 8 + nl0;
            int node = ntile + hh * 32 + node_l;
            if (node < n) {
                h8 v = *(const h8*)(slab + node_l * LSTR + chunk * 8);
                *(h8*)(CB + ((size_t)ks * n + node) * 64 + chunk * 8) = v;
            }
        }
        // DS ops in-order per wave: hh=1 restage cannot pass the reads above.
    }
}

// ---------------- small-layer GEMM: block = KK waves, wave k, lane = node -------------
template <int KK, int DIN4, int NACC>
__global__ void gemm_smallw_kernel(const float* __restrict__ X, const float* __restrict__ Wp,
                                   const float* __restrict__ bias, int dout,
                                   half4* __restrict__ CB, int n) {
    int lane = threadIdx.x & 63;
    int k = __builtin_amdgcn_readfirstlane((int)(threadIdx.x >> 6));
    int node0 = blockIdx.x * 64 + lane;
    int node = min(node0, n - 1);
    f4 acc[NACC];
#pragma unroll
    for (int i = 0; i < NACC; ++i) {
        f4 v = {0.f, 0.f, 0.f, 0.f};
        if (k == 0 && bias) {
#pragma unroll
            for (int c = 0; c < 4; ++c) {
                int o = i * 4 + c;
                v[c] = (o < dout) ? bias[o] : 0.f;
            }
        }
        acc[i] = v;
    }
    const f4* Xr = (const f4*)(X + (size_t)node * (DIN4 * 4));
    const f4* Wk = (const f4*)(Wp + (size_t)k * (DIN4 * 4) * (NACC * 4));
    for (int d4 = 0; d4 < DIN4; ++d4) {
        f4 xv = Xr[d4];
#pragma unroll
        for (int j = 0; j < 4; ++j) {
            float xs = xv[j];
#pragma unroll
            for (int i = 0; i < NACC; ++i)
                acc[i] += xs * Wk[(d4 * 4 + j) * NACC + i];
        }
    }
    if (node0 < n) {
        size_t base = ((size_t)k * n + node) * NACC;
#pragma unroll
        for (int i = 0; i < NACC; ++i) {
            half4 h;
            h.x = (half1)acc[i].x; h.y = (half1)acc[i].y;
            h.z = (half1)acc[i].z; h.w = (half1)acc[i].w;
            CB[base + i] = h;
        }
    }
}

// ---------------- host driver ----------------

extern "C" void kernel_launch(void* const* d_in, const int* in_sizes, int n_in,
                              void* d_out, int out_size, void* d_ws, size_t ws_size,
                              hipStream_t stream) {
    const float* x  = (const float*)d_in[0];
    const int*   ei = (const int*)d_in[1];
    const float* Wl[4] = {(const float*)d_in[2], (const float*)d_in[4],
                          (const float*)d_in[6], (const float*)d_in[8]};
    const float* bl[4] = {(const float*)d_in[3], (const float*)d_in[5],
                          (const float*)d_in[7], (const float*)d_in[9]};
    const float* bn[3][4];
    for (int l = 0; l < 3; ++l)
        for (int j = 0; j < 4; ++j)
            bn[l][j] = (const float*)d_in[10 + 4 * l + j];

    char* ws = (char*)d_ws;
    size_t off = 0;
    auto alloc = [&](size_t bytes) -> void* {
        void* p = (void*)(ws + off);
        off = (off + bytes + 255) & ~(size_t)255;
        return p;
    };
    int*   deg      = (int*)alloc(NN * 4);
    int*   row_ptr  = (int*)alloc((NN + 1) * 4);
    int*   bstart   = (int*)alloc((NBUCK + 1) * 4);
    unsigned int* cw = (unsigned int*)alloc((size_t)NE * 4);
    half1* CB1h    = (half1*)alloc((size_t)8 * NN * 64 * 2);
    half1* CBsh    = (half1*)alloc((size_t)6 * NN * 20 * 2);
    half1* S0      = (half1*)alloc((size_t)NN * 64 * 2);
    half1* S1      = (half1*)alloc((size_t)NN * 64 * 2);
    half1* S2      = (half1*)alloc((size_t)NN * 64 * 2);
    float* H1f     = (float*)alloc((size_t)NN * 64 * 4);
    float* H2f     = (float*)alloc((size_t)NN * 20 * 4);
    float* H3f     = (float*)alloc((size_t)NN * 12 * 4);
    float* Wp2     = (float*)alloc((size_t)6 * 64 * 20 * 4);
    float* Wp3     = (float*)alloc((size_t)4 * 20 * 12 * 4);
    float* Wp4     = (float*)alloc((size_t)4 * 12 * 12 * 4);
    half1* Xh      = (half1*)alloc((size_t)NN * 128 * 2);
    half1* Wt1     = (half1*)alloc((size_t)512 * 128 * 2);

    // CSR-build scratch aliased into CB1h (consumed before gemm_mfma writes it):
    unsigned int* tmp = (unsigned int*)CB1h;                // 6.4 MB
    int* hist_g = (int*)((char*)CB1h + (16u << 20));        // NC*NBUCK*4 = 600 KB
    int* off_g  = hist_g + NC * NBUCK;                      // 600 KB

    const int* srcp = ei;
    const int* dstp = ei + NE;
    const int NB = divup(NN, 64);

    histb_kernel<<<NC, 256, 0, stream>>>(dstp, hist_g);
    bscan1_kernel<<<1, 1024, 0, stream>>>(hist_g, bstart, row_ptr);
    boff_kernel<<<divup(NBUCK, 256), 256, 0, stream>>>(bstart, hist_g, off_g);
    binscatter_kernel<<<NC * 8, 256, 0, stream>>>(srcp, dstp, off_g, tmp);
    finalize_kernel<<<NBUCK, 256, 0, stream>>>(tmp, bstart, row_ptr, deg, cw);
    packdeg_kernel<<<divup(NE, 256), 256, 0, stream>>>(cw, deg);

    cvtx_kernel<<<divup(NN * 32, 256), 256, 0, stream>>>((const float4*)x, (half4*)Xh, NN * 32);
    transw_kernel<<<divup(512 * 128, 256), 256, 0, stream>>>(Wl[0], Wt1);
    padw_kernel<<<divup(6 * 64 * 20, 256), 256, 0, stream>>>(Wl[1], Wp2, 6, 64, 18, 64, 20);
    padw_kernel<<<divup(4 * 20 * 12, 256), 256, 0, stream>>>(Wl[2], Wp3, 4, 18, 9, 20, 12);
    padw_kernel<<<divup(4 * 12 * 12, 256), 256, 0, stream>>>(Wl[3], Wp4, 4, 9, 10, 12, 12);

    // dim-64 prop (h8 gathers)
    auto prop1 = [&](const half1* feat, const half1* sub, const half1* add,
                     half1* outh, float* outf, float scale, int bnrelu,
                     const float* g, const float* bb, const float* m, const float* v) {
        proph8_kernel<<<divup(NN * 8, 256), 256, 0, stream>>>(
            (const h8*)feat, (const h8*)sub, (const h8*)add,
            (h8*)outh, (f8*)outf, row_ptr, cw, NN, scale,
            sub != nullptr, bnrelu, g, bb, m, v);
    };
    // small-dim prop (half4 gathers)
    auto prop = [&](const half1* feat, const half1* sub, const half1* add,
                    half1* outh, float* outf, int dim4, float scale,
                    int bnrelu, int used, const float* g, const float* bb,
                    const float* m, const float* v) {
        proph_kernel<<<divup(NN * dim4, 256), 256, 0, stream>>>(
            (const half4*)feat, (const half4*)sub, (const half4*)add,
            (half4*)outh, (f4*)outf, row_ptr, cw, NN, dim4, scale,
            sub != nullptr, bnrelu, used, g, bb, m, v);
    };

    // ---- layer 1 (din=128, dout=64, K=8) -> H1f ----
    gemm_mfma_kernel<<<NB, 512, 0, stream>>>(Xh, Wt1, bl[0], CB1h, NN);
    {
        auto C = [&](int k) { return (const half1*)(CB1h + (size_t)k * NN * 64); };
        prop1(C(7), nullptr, C(6), S0, nullptr, 2.f, 0, 0, 0, 0, 0);
        prop1(S0, C(7), C(5), S1, nullptr, 2.f, 0, 0, 0, 0, 0);
        prop1(S1, S0, C(4), S2, nullptr, 2.f, 0, 0, 0, 0, 0);
        prop1(S2, S1, C(3), S0, nullptr, 2.f, 0, 0, 0, 0, 0);
        prop1(S0, S2, C(2), S1, nullptr, 2.f, 0, 0, 0, 0, 0);
        prop1(S1, S0, C(1), S2, nullptr, 2.f, 0, 0, 0, 0, 0);
        prop1(S2, S1, C(0), nullptr, H1f, 1.f, 1,
              bn[0][0], bn[0][1], bn[0][2], bn[0][3]);
    }

    // ---- layer 2 (din=64, dout=18 pad 20, K=6): X=H1f -> H2f ----
    gemm_smallw_kernel<6, 16, 5><<<NB, 384, 0, stream>>>(H1f, Wp2, bl[1], 18,
                                                         (half4*)CBsh, NN);
    {
        auto C = [&](int k) { return (const half1*)(CBsh + (size_t)k * NN * 20); };
        prop(C(5), nullptr, C(4), S0, nullptr, 5, 2.f, 0, 18, 0, 0, 0, 0);
        prop(S0, C(5), C(3), S1, nullptr, 5, 2.f, 0, 18, 0, 0, 0, 0);
        prop(S1, S0, C(2), S2, nullptr, 5, 2.f, 0, 18, 0, 0, 0, 0);
        prop(S2, S1, C(1), S0, nullptr, 5, 2.f, 0, 18, 0, 0, 0, 0);
        prop(S0, S2, C(0), nullptr, H2f, 5, 1.f, 1, 18,
             bn[1][0], bn[1][1], bn[1][2], bn[1][3]);
    }

    // ---- layer 3 (din=18 str20, dout=9 pad 12, K=4): X=H2f -> H3f ----
    gemm_smallw_kernel<4, 5, 3><<<NB, 256, 0, stream>>>(H2f, Wp3, bl[2], 9,
                                                        (half4*)CBsh, NN);
    {
        auto C = [&](int k) { return (const half1*)(CBsh + (size_t)k * NN * 12); };
        prop(C(3), nullptr, C(2), S0, nullptr, 3, 2.f, 0, 9, 0, 0, 0, 0);
        prop(S0, C(3), C(1), S1, nullptr, 3, 2.f, 0, 9, 0, 0, 0, 0);
        prop(S1, S0, C(0), nullptr, H3f, 3, 1.f, 1, 9,
             bn[2][0], bn[2][1], bn[2][2], bn[2][3]);
    }

    // ---- layer 4 (din=9 str12, dout=10 pad 12, K=4): X=H3f -> d_out ----
    gemm_smallw_kernel<4, 3, 3><<<NB, 256, 0, stream>>>(H3f, Wp4, bl[3], 10,
                                                        (half4*)CBsh, NN);
    {
        auto C = [&](int k) { return (const half1*)(CBsh + (size_t)k * NN * 12); };
        prop(C(3), nullptr, C(2), S0, nullptr, 3, 2.f, 0, 10, 0, 0, 0, 0);
        prop(S0, C(3), C(1), S1, nullptr, 3, 2.f, 0, 10, 0, 0, 0, 0);
        propl_kernel<<<divup(NN * 3, 256), 256, 0, stream>>>(
            (const half4*)S1, (const half4*)S0, (const half4*)CBsh,
            (float*)d_out, row_ptr, cw, NN);
    }
}

// Round 11
// 773.738 us; speedup vs baseline: 1.4627x; 1.0175x over previous
//
#include <hip/hip_runtime.h>

#define NN 100000
#define NE 1600000
#define BN_EPS 1e-5f

// CSR binning parameters
#define BSH 7
#define BSZ (1 << BSH)   // 128 dsts per bucket
#define NBUCK 782        // divup(NN, BSZ)
#define NC 192           // edge chunks
#define CE 8334          // divup(NE, NC)

typedef _Float16 half1;
typedef _Float16 half4 __attribute__((ext_vector_type(4)));
typedef _Float16 h8 __attribute__((ext_vector_type(8)));
typedef float f4 __attribute__((ext_vector_type(4)));
typedef float f8 __attribute__((ext_vector_type(8)));

static inline int divup(int a, int b) { return (a + b - 1) / b; }

// per-edge source weight from packed entry: src in [0:17), deg_src in [17:32)
__device__ __forceinline__ float wsrc(unsigned int q) {
    unsigned int dg = q >> 17;
    return dg ? rsqrtf((float)dg) : 0.f;
}

// ---------------- preprocessing (no global atomics) ----------------

__global__ void histb_kernel(const int* __restrict__ dst, int* __restrict__ hist_g) {
    __shared__ int h[NBUCK];
    int c = blockIdx.x;
    for (int i = threadIdx.x; i < NBUCK; i += blockDim.x) h[i] = 0;
    __syncthreads();
    int e0 = c * CE, e1 = min(e0 + CE, NE);
    for (int e = e0 + threadIdx.x; e < e1; e += blockDim.x)
        atomicAdd(&h[dst[e] >> BSH], 1);
    __syncthreads();
    for (int i = threadIdx.x; i < NBUCK; i += blockDim.x) hist_g[c * NBUCK + i] = h[i];
}

__global__ void bscan1_kernel(const int* __restrict__ hist_g, int* __restrict__ bucket_start,
                              int* __restrict__ row_ptr) {
    __shared__ int sh[1024];
    int t = threadIdx.x;
    int tot = 0;
    if (t < NBUCK)
        for (int c = 0; c < NC; ++c) tot += hist_g[c * NBUCK + t];
    sh[t] = (t < NBUCK) ? tot : 0;
    __syncthreads();
    for (int off = 1; off < 1024; off <<= 1) {
        int v = (t >= off) ? sh[t - off] : 0;
        __syncthreads();
        sh[t] += v;
        __syncthreads();
    }
    if (t < NBUCK) bucket_start[t] = sh[t] - tot;
    if (t == 0) { bucket_start[NBUCK] = NE; row_ptr[NN] = NE; }
}

__global__ void boff_kernel(const int* __restrict__ bucket_start, const int* __restrict__ hist_g,
                            int* __restrict__ off_g) {
    int b = blockIdx.x * blockDim.x + threadIdx.x;
    if (b >= NBUCK) return;
    int run = bucket_start[b];
#pragma unroll 4
    for (int c = 0; c < NC; ++c) {
        off_g[c * NBUCK + b] = run;
        run += hist_g[c * NBUCK + b];
    }
}

__global__ void binscatter_kernel(const int* __restrict__ src, const int* __restrict__ dst,
                                  const int* __restrict__ off_g, unsigned int* __restrict__ tmp) {
    __shared__ int off_l[NBUCK];
    int myx = blockIdx.x & 7;
    int c = blockIdx.x >> 3;
    for (int i = threadIdx.x; i < NBUCK; i += blockDim.x)
        off_l[i] = ((i & 7) == myx) ? off_g[c * NBUCK + i] : 0;
    __syncthreads();
    int e0 = c * CE, e1 = min(e0 + CE, NE);
    for (int e = e0 + threadIdx.x; e < e1; e += blockDim.x) {
        int d = dst[e];
        int b = d >> BSH;
        if ((b & 7) != myx) continue;
        int s = src[e];
        int pos = atomicAdd(&off_l[b], 1);
        tmp[pos] = (unsigned int)s | ((unsigned int)(d & (BSZ - 1)) << 25);
    }
}

__global__ void finalize_kernel(const unsigned int* __restrict__ tmp,
                                const int* __restrict__ bucket_start,
                                int* __restrict__ row_ptr, int* __restrict__ deg,
                                unsigned int* __restrict__ cw) {
    __shared__ int cnt[BSZ], sc[BSZ], cur[BSZ];
    int b = blockIdx.x, t = threadIdx.x;
    int e0 = bucket_start[b], e1 = bucket_start[b + 1];
    if (t < BSZ) cnt[t] = 0;
    __syncthreads();
    for (int e = e0 + t; e < e1; e += blockDim.x) atomicAdd(&cnt[tmp[e] >> 25], 1);
    __syncthreads();
    if (t < BSZ) sc[t] = cnt[t];
    __syncthreads();
    for (int off = 1; off < BSZ; off <<= 1) {
        int v = (t >= off && t < BSZ) ? sc[t - off] : 0;
        __syncthreads();
        if (t < BSZ) sc[t] += v;
        __syncthreads();
    }
    if (t < BSZ) {
        int p = e0 + sc[t] - cnt[t];
        cur[t] = p;
        int nd = (b << BSH) + t;
        if (nd < NN) { row_ptr[nd] = p; deg[nd] = cnt[t]; }
    }
    __syncthreads();
    for (int e = e0 + t; e < e1; e += blockDim.x) {
        unsigned int r = tmp[e];
        int ld = r >> 25;
        int k = atomicAdd(&cur[ld], 1);
        cw[k] = r & 0x1FFFFu;
    }
}

__global__ void packdeg_kernel(unsigned int* __restrict__ cw, const int* __restrict__ deg) {
    int e = blockIdx.x * blockDim.x + threadIdx.x;
    if (e >= NE) return;
    unsigned int q = cw[e];
    int dg = deg[q];
    if (dg > 32767) dg = 32767;
    cw[e] = q | ((unsigned int)dg << 17);
}

// ---------------- fp16 converts for MFMA ----------------

__global__ void cvtx_kernel(const float4* __restrict__ X, half4* __restrict__ Xh, int tot4) {
    int i = blockIdx.x * blockDim.x + threadIdx.x;
    if (i >= tot4) return;
    float4 v = X[i];
    half4 h;
    h.x = (half1)v.x; h.y = (half1)v.y; h.z = (half1)v.z; h.w = (half1)v.w;
    Xh[i] = h;
}

// Wt[og][kd] = W1[og>>6][kd][og&63], fp16 ; Wt is [512][128]
__global__ void transw_kernel(const float* __restrict__ W, half1* __restrict__ Wt) {
    int i = blockIdx.x * blockDim.x + threadIdx.x;
    if (i >= 512 * 128) return;
    int kd = i >> 9;
    int og = i & 511;
    int k = og >> 6, o = og & 63;
    Wt[(size_t)og * 128 + kd] = (half1)W[((size_t)k * 128 + kd) * 64 + o];
}

// ---------------- W padding ----------------
__global__ void padw_kernel(const float* __restrict__ src, float* __restrict__ dst,
                            int K, int dins, int douts, int dind, int doutd) {
    int i = blockIdx.x * blockDim.x + threadIdx.x;
    int tot = K * dind * doutd;
    if (i >= tot) return;
    int o = i % doutd;
    int r = i / doutd;
    int dd = r % dind;
    int k = r / dind;
    dst[i] = (dd < dins && o < douts) ? src[((size_t)k * dins + dd) * douts + o] : 0.f;
}

// ---------------- Clenshaw prop, h8 (16B) gathers — dim == 64 ----------------
// R9 form: 2 accumulators, scalar cw loads (broadcast-served across the 8
// f-lanes of a node; R10 showed uint4+align-prologue costs ~3.5us/pass).
__global__ void proph8_kernel(const h8* __restrict__ feat, const h8* __restrict__ sub,
                              const h8* __restrict__ add, h8* __restrict__ outh,
                              f8* __restrict__ outf,
                              const int* __restrict__ row_ptr, const unsigned int* __restrict__ cw,
                              int n, float scale, int has_sub, int bnrelu,
                              const float* __restrict__ bn_g, const float* __restrict__ bn_b,
                              const float* __restrict__ bn_m, const float* __restrict__ bn_v) {
    int idx = blockIdx.x * blockDim.x + threadIdx.x;
    if (idx >= n * 8) return;
    int nd = idx >> 3;
    int f = idx & 7;
    int e0 = row_ptr[nd], e1 = row_ptr[nd + 1];
    f8 a0 = {0.f, 0.f, 0.f, 0.f, 0.f, 0.f, 0.f, 0.f}, a1 = a0;
    int e = e0;
    for (; e + 4 <= e1; e += 4) {
        unsigned int q0 = cw[e], q1 = cw[e + 1], q2 = cw[e + 2], q3 = cw[e + 3];
        h8 h0 = feat[(size_t)(q0 & 0x1FFFFu) * 8 + f];
        h8 h1 = feat[(size_t)(q1 & 0x1FFFFu) * 8 + f];
        h8 h2 = feat[(size_t)(q2 & 0x1FFFFu) * 8 + f];
        h8 h3 = feat[(size_t)(q3 & 0x1FFFFu) * 8 + f];
        a0 += wsrc(q0) * __builtin_convertvector(h0, f8);
        a1 += wsrc(q1) * __builtin_convertvector(h1, f8);
        a0 += wsrc(q2) * __builtin_convertvector(h2, f8);
        a1 += wsrc(q3) * __builtin_convertvector(h3, f8);
    }
    for (; e < e1; ++e) {
        unsigned int q = cw[e];
        a0 += wsrc(q) * __builtin_convertvector(feat[(size_t)(q & 0x1FFFFu) * 8 + f], f8);
    }
    int degd = e1 - e0;
    float ms = (degd > 0) ? -scale * rsqrtf((float)degd) : 0.f;
    f8 r = (a0 + a1) * ms;
    if (has_sub) r -= __builtin_convertvector(__builtin_nontemporal_load(&sub[idx]), f8);
    r += __builtin_convertvector(__builtin_nontemporal_load(&add[idx]), f8);
    if (bnrelu) {
#pragma unroll
        for (int c = 0; c < 8; ++c) {
            int o = f * 8 + c;
            float sc = bn_g[o] * rsqrtf(bn_v[o] + BN_EPS);
            r[c] = fmaxf(fmaf(r[c] - bn_m[o], sc, bn_b[o]), 0.f);
        }
    }
    if (outf) {
        outf[idx] = r;
    } else {
        outh[idx] = __builtin_convertvector(r, h8);
    }
}

// ---------------- Clenshaw prop, half4 gathers — small dims ----------------
__global__ void proph_kernel(const half4* __restrict__ feat, const half4* __restrict__ sub,
                             const half4* __restrict__ add, half4* __restrict__ outh,
                             f4* __restrict__ outf,
                             const int* __restrict__ row_ptr, const unsigned int* __restrict__ cw,
                             int n, int dim4, float scale, int has_sub,
                             int bnrelu, int used,
                             const float* __restrict__ bn_g, const float* __restrict__ bn_b,
                             const float* __restrict__ bn_m, const float* __restrict__ bn_v) {
    int idx = blockIdx.x * blockDim.x + threadIdx.x;
    if (idx >= n * dim4) return;
    int nd = idx / dim4;
    int f = idx - nd * dim4;
    int e0 = row_ptr[nd], e1 = row_ptr[nd + 1];
    f4 a0 = {0.f, 0.f, 0.f, 0.f}, a1 = a0, a2 = a0, a3 = a0;
    int e = e0;
    for (; e + 4 <= e1; e += 4) {
        unsigned int q0 = cw[e], q1 = cw[e + 1], q2 = cw[e + 2], q3 = cw[e + 3];
        f4 v0 = __builtin_convertvector(feat[(size_t)(q0 & 0x1FFFFu) * dim4 + f], f4);
        f4 v1 = __builtin_convertvector(feat[(size_t)(q1 & 0x1FFFFu) * dim4 + f], f4);
        f4 v2 = __builtin_convertvector(feat[(size_t)(q2 & 0x1FFFFu) * dim4 + f], f4);
        f4 v3 = __builtin_convertvector(feat[(size_t)(q3 & 0x1FFFFu) * dim4 + f], f4);
        a0 += wsrc(q0) * v0;
        a1 += wsrc(q1) * v1;
        a2 += wsrc(q2) * v2;
        a3 += wsrc(q3) * v3;
    }
    for (; e < e1; ++e) {
        unsigned int q = cw[e];
        a0 += wsrc(q) * __builtin_convertvector(feat[(size_t)(q & 0x1FFFFu) * dim4 + f], f4);
    }
    int degd = e1 - e0;
    float ms = (degd > 0) ? -scale * rsqrtf((float)degd) : 0.f;
    f4 r = ((a0 + a1) + (a2 + a3)) * ms;
    if (has_sub) r -= __builtin_convertvector(__builtin_nontemporal_load(&sub[idx]), f4);
    r += __builtin_convertvector(__builtin_nontemporal_load(&add[idx]), f4);
    if (bnrelu) {
#pragma unroll
        for (int c = 0; c < 4; ++c) {
            int o = f * 4 + c;
            if (o < used) {
                float sc = bn_g[o] * rsqrtf(bn_v[o] + BN_EPS);
                r[c] = fmaxf(fmaf(r[c] - bn_m[o], sc, bn_b[o]), 0.f);
            } else r[c] = 0.f;
        }
    }
    if (outf) {
        outf[idx] = r;
    } else {
        half4 h;
        h.x = (half1)r.x; h.y = (half1)r.y; h.z = (half1)r.z; h.w = (half1)r.w;
        outh[idx] = h;
    }
}

// layer-4 final: fp16 gathers/streams at stride 12 (dim4=3), fp32 out at stride 10
__global__ void propl_kernel(const half4* __restrict__ feat, const half4* __restrict__ sub,
                             const half4* __restrict__ add, float* __restrict__ out,
                             const int* __restrict__ row_ptr, const unsigned int* __restrict__ cw,
                             int n) {
    int idx = blockIdx.x * blockDim.x + threadIdx.x;
    if (idx >= n * 3) return;
    int nd = idx / 3;
    int f = idx - nd * 3;
    int e0 = row_ptr[nd], e1 = row_ptr[nd + 1];
    f4 a0 = {0.f, 0.f, 0.f, 0.f}, a1 = a0, a2 = a0, a3 = a0;
    int e = e0;
    for (; e + 4 <= e1; e += 4) {
        unsigned int q0 = cw[e], q1 = cw[e + 1], q2 = cw[e + 2], q3 = cw[e + 3];
        a0 += wsrc(q0) * __builtin_convertvector(feat[(size_t)(q0 & 0x1FFFFu) * 3 + f], f4);
        a1 += wsrc(q1) * __builtin_convertvector(feat[(size_t)(q1 & 0x1FFFFu) * 3 + f], f4);
        a2 += wsrc(q2) * __builtin_convertvector(feat[(size_t)(q2 & 0x1FFFFu) * 3 + f], f4);
        a3 += wsrc(q3) * __builtin_convertvector(feat[(size_t)(q3 & 0x1FFFFu) * 3 + f], f4);
    }
    for (; e < e1; ++e) {
        unsigned int q = cw[e];
        a0 += wsrc(q) * __builtin_convertvector(feat[(size_t)(q & 0x1FFFFu) * 3 + f], f4);
    }
    int degd = e1 - e0;
    float ms = (degd > 0) ? -rsqrtf((float)degd) : 0.f;
    f4 r = ((a0 + a1) + (a2 + a3)) * ms;
    r -= __builtin_convertvector(sub[idx], f4);
    r += __builtin_convertvector(add[idx], f4);
    int o = f * 4;
    float* orow = out + (size_t)nd * 10;
    if (o + 0 < 10) orow[o + 0] = r.x;
    if (o + 1 < 10) orow[o + 1] = r.y;
    if (o + 2 < 10) orow[o + 2] = r.z;
    if (o + 3 < 10) orow[o + 3] = r.w;
}

// ---------------- layer-1 GEMM via MFMA (8 waves = 8 k-slices, 64-node tile) --------
// R5 structure (verified 72us, 0 conflicts): fp16 Xh input, per-wave LDS slab,
// no barriers, LSTR=68.
#define LSTR 68
__global__ __launch_bounds__(512) void gemm_mfma_kernel(
        const half1* __restrict__ Xh, const half1* __restrict__ Wt,
        const float* __restrict__ bias, half1* __restrict__ CB, int n) {
    __shared__ half1 lds[8 * 32 * LSTR];  // 34816 B
    int lane = threadIdx.x & 63;
    int ks = threadIdx.x >> 6;   // 0..7
    int m16 = lane & 15;
    int quad = lane >> 4;
    int ntile = blockIdx.x * 64;

    f4 acc[4][4];
#pragma unroll
    for (int nt = 0; nt < 4; ++nt)
#pragma unroll
        for (int i = 0; i < 4; ++i) acc[nt][i] = (f4){0.f, 0.f, 0.f, 0.f};

#pragma unroll
    for (int kc = 0; kc < 4; ++kc) {
        int koff = kc * 32 + quad * 8;
        h8 a[4];
#pragma unroll
        for (int i = 0; i < 4; ++i)
            a[i] = *(const h8*)(Wt + (size_t)(ks * 64 + i * 16 + m16) * 128 + koff);
        h8 b[4];
#pragma unroll
        for (int nt = 0; nt < 4; ++nt) {
            int node = min(ntile + nt * 16 + m16, n - 1);
            b[nt] = *(const h8*)(Xh + (size_t)node * 128 + koff);
        }
#pragma unroll
        for (int nt = 0; nt < 4; ++nt)
#pragma unroll
            for (int i = 0; i < 4; ++i)
                acc[nt][i] = __builtin_amdgcn_mfma_f32_16x16x32_f16(a[i], b[nt], acc[nt][i], 0, 0, 0);
    }

    half1* slab = lds + (size_t)ks * 32 * LSTR;
    int nl0 = lane >> 3;    // 0..7
    int chunk = lane & 7;   // 0..7, 16B each
#pragma unroll
    for (int hh = 0; hh < 2; ++hh) {
        // stage 32 nodes (nt = 2*hh, 2*hh+1) into this wave's slab
#pragma unroll
        for (int p = 0; p < 2; ++p) {
            int nt = hh * 2 + p;
            int node_l = p * 16 + m16;
#pragma unroll
            for (int i = 0; i < 4; ++i) {
                int ob = i * 16 + quad * 4;
                f4 v = acc[nt][i];
                if (ks == 0) {
                    const f4 b4 = *(const f4*)(bias + ob);
                    v += b4;
                }
                half4 h;
                h.x = (half1)v[0]; h.y = (half1)v[1]; h.z = (half1)v[2]; h.w = (half1)v[3];
                *(half4*)(slab + node_l * LSTR + ob) = h;
            }
        }
        asm volatile("s_waitcnt lgkmcnt(0)" ::: "memory");  // cross-lane RAW within wave
        // coalesced copy-out: 8 lanes per 128B node row
#pragma unroll
        for (int j = 0; j < 4; ++j) {
            int node_l = j * 8 + nl0;
            int node = ntile + hh * 32 + node_l;
            if (node < n) {
                h8 v = *(const h8*)(slab + node_l * LSTR + chunk * 8);
                *(h8*)(CB + ((size_t)ks * n + node) * 64 + chunk * 8) = v;
            }
        }
        // DS ops in-order per wave: hh=1 restage cannot pass the reads above.
    }
}

// ---------------- small-layer GEMM: block = KK waves, wave k, lane = node -------------
template <int KK, int DIN4, int NACC>
__global__ void gemm_smallw_kernel(const float* __restrict__ X, const float* __restrict__ Wp,
                                   const float* __restrict__ bias, int dout,
                                   half4* __restrict__ CB, int n) {
    int lane = threadIdx.x & 63;
    int k = __builtin_amdgcn_readfirstlane((int)(threadIdx.x >> 6));
    int node0 = blockIdx.x * 64 + lane;
    int node = min(node0, n - 1);
    f4 acc[NACC];
#pragma unroll
    for (int i = 0; i < NACC; ++i) {
        f4 v = {0.f, 0.f, 0.f, 0.f};
        if (k == 0 && bias) {
#pragma unroll
            for (int c = 0; c < 4; ++c) {
                int o = i * 4 + c;
                v[c] = (o < dout) ? bias[o] : 0.f;
            }
        }
        acc[i] = v;
    }
    const f4* Xr = (const f4*)(X + (size_t)node * (DIN4 * 4));
    const f4* Wk = (const f4*)(Wp + (size_t)k * (DIN4 * 4) * (NACC * 4));
    for (int d4 = 0; d4 < DIN4; ++d4) {
        f4 xv = Xr[d4];
#pragma unroll
        for (int j = 0; j < 4; ++j) {
            float xs = xv[j];
#pragma unroll
            for (int i = 0; i < NACC; ++i)
                acc[i] += xs * Wk[(d4 * 4 + j) * NACC + i];
        }
    }
    if (node0 < n) {
        size_t base = ((size_t)k * n + node) * NACC;
#pragma unroll
        for (int i = 0; i < NACC; ++i) {
            half4 h;
            h.x = (half1)acc[i].x; h.y = (half1)acc[i].y;
            h.z = (half1)acc[i].z; h.w = (half1)acc[i].w;
            CB[base + i] = h;
        }
    }
}

// ---------------- host driver ----------------

extern "C" void kernel_launch(void* const* d_in, const int* in_sizes, int n_in,
                              void* d_out, int out_size, void* d_ws, size_t ws_size,
                              hipStream_t stream) {
    const float* x  = (const float*)d_in[0];
    const int*   ei = (const int*)d_in[1];
    const float* Wl[4] = {(const float*)d_in[2], (const float*)d_in[4],
                          (const float*)d_in[6], (const float*)d_in[8]};
    const float* bl[4] = {(const float*)d_in[3], (const float*)d_in[5],
                          (const float*)d_in[7], (const float*)d_in[9]};
    const float* bn[3][4];
    for (int l = 0; l < 3; ++l)
        for (int j = 0; j < 4; ++j)
            bn[l][j] = (const float*)d_in[10 + 4 * l + j];

    char* ws = (char*)d_ws;
    size_t off = 0;
    auto alloc = [&](size_t bytes) -> void* {
        void* p = (void*)(ws + off);
        off = (off + bytes + 255) & ~(size_t)255;
        return p;
    };
    int*   deg      = (int*)alloc(NN * 4);
    int*   row_ptr  = (int*)alloc((NN + 1) * 4);
    int*   bstart   = (int*)alloc((NBUCK + 1) * 4);
    unsigned int* cw = (unsigned int*)alloc((size_t)NE * 4);
    half1* CB1h    = (half1*)alloc((size_t)8 * NN * 64 * 2);
    half1* CBsh    = (half1*)alloc((size_t)6 * NN * 20 * 2);
    half1* S0      = (half1*)alloc((size_t)NN * 64 * 2);
    half1* S1      = (half1*)alloc((size_t)NN * 64 * 2);
    half1* S2      = (half1*)alloc((size_t)NN * 64 * 2);
    float* H1f     = (float*)alloc((size_t)NN * 64 * 4);
    float* H2f     = (float*)alloc((size_t)NN * 20 * 4);
    float* H3f     = (float*)alloc((size_t)NN * 12 * 4);
    float* Wp2     = (float*)alloc((size_t)6 * 64 * 20 * 4);
    float* Wp3     = (float*)alloc((size_t)4 * 20 * 12 * 4);
    float* Wp4     = (float*)alloc((size_t)4 * 12 * 12 * 4);
    half1* Xh      = (half1*)alloc((size_t)NN * 128 * 2);
    half1* Wt1     = (half1*)alloc((size_t)512 * 128 * 2);

    // CSR-build scratch aliased into CB1h (consumed before gemm_mfma writes it):
    unsigned int* tmp = (unsigned int*)CB1h;                // 6.4 MB
    int* hist_g = (int*)((char*)CB1h + (16u << 20));        // NC*NBUCK*4 = 600 KB
    int* off_g  = hist_g + NC * NBUCK;                      // 600 KB

    const int* srcp = ei;
    const int* dstp = ei + NE;
    const int NB = divup(NN, 64);

    histb_kernel<<<NC, 256, 0, stream>>>(dstp, hist_g);
    bscan1_kernel<<<1, 1024, 0, stream>>>(hist_g, bstart, row_ptr);
    boff_kernel<<<divup(NBUCK, 256), 256, 0, stream>>>(bstart, hist_g, off_g);
    binscatter_kernel<<<NC * 8, 256, 0, stream>>>(srcp, dstp, off_g, tmp);
    finalize_kernel<<<NBUCK, 256, 0, stream>>>(tmp, bstart, row_ptr, deg, cw);
    packdeg_kernel<<<divup(NE, 256), 256, 0, stream>>>(cw, deg);

    cvtx_kernel<<<divup(NN * 32, 256), 256, 0, stream>>>((const float4*)x, (half4*)Xh, NN * 32);
    transw_kernel<<<divup(512 * 128, 256), 256, 0, stream>>>(Wl[0], Wt1);
    padw_kernel<<<divup(6 * 64 * 20, 256), 256, 0, stream>>>(Wl[1], Wp2, 6, 64, 18, 64, 20);
    padw_kernel<<<divup(4 * 20 * 12, 256), 256, 0, stream>>>(Wl[2], Wp3, 4, 18, 9, 20, 12);
    padw_kernel<<<divup(4 * 12 * 12, 256), 256, 0, stream>>>(Wl[3], Wp4, 4, 9, 10, 12, 12);

    // dim-64 prop (h8 gathers)
    auto prop1 = [&](const half1* feat, const half1* sub, const half1* add,
                     half1* outh, float* outf, float scale, int bnrelu,
                     const float* g, const float* bb, const float* m, const float* v) {
        proph8_kernel<<<divup(NN * 8, 256), 256, 0, stream>>>(
            (const h8*)feat, (const h8*)sub, (const h8*)add,
            (h8*)outh, (f8*)outf, row_ptr, cw, NN, scale,
            sub != nullptr, bnrelu, g, bb, m, v);
    };
    // small-dim prop (half4 gathers)
    auto prop = [&](const half1* feat, const half1* sub, const half1* add,
                    half1* outh, float* outf, int dim4, float scale,
                    int bnrelu, int used, const float* g, const float* bb,
                    const float* m, const float* v) {
        proph_kernel<<<divup(NN * dim4, 256), 256, 0, stream>>>(
            (const half4*)feat, (const half4*)sub, (const half4*)add,
            (half4*)outh, (f4*)outf, row_ptr, cw, NN, dim4, scale,
            sub != nullptr, bnrelu, used, g, bb, m, v);
    };

    // ---- layer 1 (din=128, dout=64, K=8) -> H1f ----
    gemm_mfma_kernel<<<NB, 512, 0, stream>>>(Xh, Wt1, bl[0], CB1h, NN);
    {
        auto C = [&](int k) { return (const half1*)(CB1h + (size_t)k * NN * 64); };
        prop1(C(7), nullptr, C(6), S0, nullptr, 2.f, 0, 0, 0, 0, 0);
        prop1(S0, C(7), C(5), S1, nullptr, 2.f, 0, 0, 0, 0, 0);
        prop1(S1, S0, C(4), S2, nullptr, 2.f, 0, 0, 0, 0, 0);
        prop1(S2, S1, C(3), S0, nullptr, 2.f, 0, 0, 0, 0, 0);
        prop1(S0, S2, C(2), S1, nullptr, 2.f, 0, 0, 0, 0, 0);
        prop1(S1, S0, C(1), S2, nullptr, 2.f, 0, 0, 0, 0, 0);
        prop1(S2, S1, C(0), nullptr, H1f, 1.f, 1,
              bn[0][0], bn[0][1], bn[0][2], bn[0][3]);
    }

    // ---- layer 2 (din=64, dout=18 pad 20, K=6): X=H1f -> H2f ----
    gemm_smallw_kernel<6, 16, 5><<<NB, 384, 0, stream>>>(H1f, Wp2, bl[1], 18,
                                                         (half4*)CBsh, NN);
    {
        auto C = [&](int k) { return (const half1*)(CBsh + (size_t)k * NN * 20); };
        prop(C(5), nullptr, C(4), S0, nullptr, 5, 2.f, 0, 18, 0, 0, 0, 0);
        prop(S0, C(5), C(3), S1, nullptr, 5, 2.f, 0, 18, 0, 0, 0, 0);
        prop(S1, S0, C(2), S2, nullptr, 5, 2.f, 0, 18, 0, 0, 0, 0);
        prop(S2, S1, C(1), S0, nullptr, 5, 2.f, 0, 18, 0, 0, 0, 0);
        prop(S0, S2, C(0), nullptr, H2f, 5, 1.f, 1, 18,
             bn[1][0], bn[1][1], bn[1][2], bn[1][3]);
    }

    // ---- layer 3 (din=18 str20, dout=9 pad 12, K=4): X=H2f -> H3f ----
    gemm_smallw_kernel<4, 5, 3><<<NB, 256, 0, stream>>>(H2f, Wp3, bl[2], 9,
                                                        (half4*)CBsh, NN);
    {
        auto C = [&](int k) { return (const half1*)(CBsh + (size_t)k * NN * 12); };
        prop(C(3), nullptr, C(2), S0, nullptr, 3, 2.f, 0, 9, 0, 0, 0, 0);
        prop(S0, C(3), C(1), S1, nullptr, 3, 2.f, 0, 9, 0, 0, 0, 0);
        prop(S1, S0, C(0), nullptr, H3f, 3, 1.f, 1, 9,
             bn[2][0], bn[2][1], bn[2][2], bn[2][3]);
    }

    // ---- layer 4 (din=9 str12, dout=10 pad 12, K=4): X=H3f -> d_out ----
    gemm_smallw_kernel<4, 3, 3><<<NB, 256, 0, stream>>>(H3f, Wp4, bl[3], 10,
                                                        (half4*)CBsh, NN);
    {
        auto C = [&](int k) { return (const half1*)(CBsh + (size_t)k * NN * 12); };
        prop(C(3), nullptr, C(2), S0, nullptr, 3, 2.f, 0, 10, 0, 0, 0, 0);
        prop(S0, C(3), C(1), S1, nullptr, 3, 2.f, 0, 10, 0, 0, 0, 0);
        propl_kernel<<<divup(NN * 3, 256), 256, 0, stream>>>(
            (const half4*)S1, (const half4*)S0, (const half4*)CBsh,
            (float*)d_out, row_ptr, cw, NN);
    }
}

// Round 12
// 765.773 us; speedup vs baseline: 1.4779x; 1.0104x over previous
//
#include <hip/hip_runtime.h>

#define NN 100000
#define NE 1600000
#define BN_EPS 1e-5f

// CSR binning parameters
#define BSH 7
#define BSZ (1 << BSH)   // 128 dsts per bucket
#define NBUCK 782        // divup(NN, BSZ)
#define NC 192           // edge chunks
#define CE 8334          // divup(NE, NC)

typedef _Float16 half1;
typedef _Float16 half4 __attribute__((ext_vector_type(4)));
typedef _Float16 h8 __attribute__((ext_vector_type(8)));
typedef float f4 __attribute__((ext_vector_type(4)));
typedef float f8 __attribute__((ext_vector_type(8)));

static inline int divup(int a, int b) { return (a + b - 1) / b; }

// per-edge source weight from packed entry: src in [0:17), deg_src in [17:32)
__device__ __forceinline__ float wsrc(unsigned int q) {
    unsigned int dg = q >> 17;
    return dg ? rsqrtf((float)dg) : 0.f;
}

// ---------------- preprocessing (no global atomics) ----------------

__global__ void histb_kernel(const int* __restrict__ dst, int* __restrict__ hist_g) {
    __shared__ int h[NBUCK];
    int c = blockIdx.x;
    for (int i = threadIdx.x; i < NBUCK; i += blockDim.x) h[i] = 0;
    __syncthreads();
    int e0 = c * CE, e1 = min(e0 + CE, NE);
    for (int e = e0 + threadIdx.x; e < e1; e += blockDim.x)
        atomicAdd(&h[dst[e] >> BSH], 1);
    __syncthreads();
    for (int i = threadIdx.x; i < NBUCK; i += blockDim.x) hist_g[c * NBUCK + i] = h[i];
}

__global__ void bscan1_kernel(const int* __restrict__ hist_g, int* __restrict__ bucket_start,
                              int* __restrict__ row_ptr) {
    __shared__ int sh[1024];
    int t = threadIdx.x;
    int tot = 0;
    if (t < NBUCK)
        for (int c = 0; c < NC; ++c) tot += hist_g[c * NBUCK + t];
    sh[t] = (t < NBUCK) ? tot : 0;
    __syncthreads();
    for (int off = 1; off < 1024; off <<= 1) {
        int v = (t >= off) ? sh[t - off] : 0;
        __syncthreads();
        sh[t] += v;
        __syncthreads();
    }
    if (t < NBUCK) bucket_start[t] = sh[t] - tot;
    if (t == 0) { bucket_start[NBUCK] = NE; row_ptr[NN] = NE; }
}

__global__ void boff_kernel(const int* __restrict__ bucket_start, const int* __restrict__ hist_g,
                            int* __restrict__ off_g) {
    int b = blockIdx.x * blockDim.x + threadIdx.x;
    if (b >= NBUCK) return;
    int run = bucket_start[b];
#pragma unroll 4
    for (int c = 0; c < NC; ++c) {
        off_g[c * NBUCK + b] = run;
        run += hist_g[c * NBUCK + b];
    }
}

__global__ void binscatter_kernel(const int* __restrict__ src, const int* __restrict__ dst,
                                  const int* __restrict__ off_g, unsigned int* __restrict__ tmp) {
    __shared__ int off_l[NBUCK];
    int myx = blockIdx.x & 7;
    int c = blockIdx.x >> 3;
    for (int i = threadIdx.x; i < NBUCK; i += blockDim.x)
        off_l[i] = ((i & 7) == myx) ? off_g[c * NBUCK + i] : 0;
    __syncthreads();
    int e0 = c * CE, e1 = min(e0 + CE, NE);
    for (int e = e0 + threadIdx.x; e < e1; e += blockDim.x) {
        int d = dst[e];
        int b = d >> BSH;
        if ((b & 7) != myx) continue;
        int s = src[e];
        int pos = atomicAdd(&off_l[b], 1);
        tmp[pos] = (unsigned int)s | ((unsigned int)(d & (BSZ - 1)) << 25);
    }
}

__global__ void finalize_kernel(const unsigned int* __restrict__ tmp,
                                const int* __restrict__ bucket_start,
                                int* __restrict__ row_ptr, int* __restrict__ deg,
                                unsigned int* __restrict__ cw) {
    __shared__ int cnt[BSZ], sc[BSZ], cur[BSZ];
    int b = blockIdx.x, t = threadIdx.x;
    int e0 = bucket_start[b], e1 = bucket_start[b + 1];
    if (t < BSZ) cnt[t] = 0;
    __syncthreads();
    for (int e = e0 + t; e < e1; e += blockDim.x) atomicAdd(&cnt[tmp[e] >> 25], 1);
    __syncthreads();
    if (t < BSZ) sc[t] = cnt[t];
    __syncthreads();
    for (int off = 1; off < BSZ; off <<= 1) {
        int v = (t >= off && t < BSZ) ? sc[t - off] : 0;
        __syncthreads();
        if (t < BSZ) sc[t] += v;
        __syncthreads();
    }
    if (t < BSZ) {
        int p = e0 + sc[t] - cnt[t];
        cur[t] = p;
        int nd = (b << BSH) + t;
        if (nd < NN) { row_ptr[nd] = p; deg[nd] = cnt[t]; }
    }
    __syncthreads();
    for (int e = e0 + t; e < e1; e += blockDim.x) {
        unsigned int r = tmp[e];
        int ld = r >> 25;
        int k = atomicAdd(&cur[ld], 1);
        cw[k] = r & 0x1FFFFu;
    }
}

__global__ void packdeg_kernel(unsigned int* __restrict__ cw, const int* __restrict__ deg) {
    int e = blockIdx.x * blockDim.x + threadIdx.x;
    if (e >= NE) return;
    unsigned int q = cw[e];
    int dg = deg[q];
    if (dg > 32767) dg = 32767;
    cw[e] = q | ((unsigned int)dg << 17);
}

// ---------------- fp16 converts for MFMA ----------------

__global__ void cvtx_kernel(const float4* __restrict__ X, half4* __restrict__ Xh, int tot4) {
    int i = blockIdx.x * blockDim.x + threadIdx.x;
    if (i >= tot4) return;
    float4 v = X[i];
    half4 h;
    h.x = (half1)v.x; h.y = (half1)v.y; h.z = (half1)v.z; h.w = (half1)v.w;
    Xh[i] = h;
}

// Wt[og][kd] = W1[og>>6][kd][og&63], fp16 ; Wt is [512][128]
__global__ void transw_kernel(const float* __restrict__ W, half1* __restrict__ Wt) {
    int i = blockIdx.x * blockDim.x + threadIdx.x;
    if (i >= 512 * 128) return;
    int kd = i >> 9;
    int og = i & 511;
    int k = og >> 6, o = og & 63;
    Wt[(size_t)og * 128 + kd] = (half1)W[((size_t)k * 128 + kd) * 64 + o];
}

// ---------------- W padding ----------------
__global__ void padw_kernel(const float* __restrict__ src, float* __restrict__ dst,
                            int K, int dins, int douts, int dind, int doutd) {
    int i = blockIdx.x * blockDim.x + threadIdx.x;
    int tot = K * dind * doutd;
    if (i >= tot) return;
    int o = i % doutd;
    int r = i / doutd;
    int dd = r % dind;
    int k = r / dind;
    dst[i] = (dd < dins && o < douts) ? src[((size_t)k * dins + dd) * douts + o] : 0.f;
}

// ---------------- Clenshaw prop, h8 (16B) gathers — dim == 64 ----------------
// R9 form: 2 accumulators, scalar cw loads (broadcast-served across the 8
// f-lanes of a node); sub/add nontemporal (read-once streams).
__global__ void proph8_kernel(const h8* __restrict__ feat, const h8* __restrict__ sub,
                              const h8* __restrict__ add, h8* __restrict__ outh,
                              f8* __restrict__ outf,
                              const int* __restrict__ row_ptr, const unsigned int* __restrict__ cw,
                              int n, float scale, int has_sub, int bnrelu,
                              const float* __restrict__ bn_g, const float* __restrict__ bn_b,
                              const float* __restrict__ bn_m, const float* __restrict__ bn_v) {
    int idx = blockIdx.x * blockDim.x + threadIdx.x;
    if (idx >= n * 8) return;
    int nd = idx >> 3;
    int f = idx & 7;
    int e0 = row_ptr[nd], e1 = row_ptr[nd + 1];
    f8 a0 = {0.f, 0.f, 0.f, 0.f, 0.f, 0.f, 0.f, 0.f}, a1 = a0;
    int e = e0;
    for (; e + 4 <= e1; e += 4) {
        unsigned int q0 = cw[e], q1 = cw[e + 1], q2 = cw[e + 2], q3 = cw[e + 3];
        h8 h0 = feat[(size_t)(q0 & 0x1FFFFu) * 8 + f];
        h8 h1 = feat[(size_t)(q1 & 0x1FFFFu) * 8 + f];
        h8 h2 = feat[(size_t)(q2 & 0x1FFFFu) * 8 + f];
        h8 h3 = feat[(size_t)(q3 & 0x1FFFFu) * 8 + f];
        a0 += wsrc(q0) * __builtin_convertvector(h0, f8);
        a1 += wsrc(q1) * __builtin_convertvector(h1, f8);
        a0 += wsrc(q2) * __builtin_convertvector(h2, f8);
        a1 += wsrc(q3) * __builtin_convertvector(h3, f8);
    }
    for (; e < e1; ++e) {
        unsigned int q = cw[e];
        a0 += wsrc(q) * __builtin_convertvector(feat[(size_t)(q & 0x1FFFFu) * 8 + f], f8);
    }
    int degd = e1 - e0;
    float ms = (degd > 0) ? -scale * rsqrtf((float)degd) : 0.f;
    f8 r = (a0 + a1) * ms;
    if (has_sub) r -= __builtin_convertvector(__builtin_nontemporal_load(&sub[idx]), f8);
    r += __builtin_convertvector(__builtin_nontemporal_load(&add[idx]), f8);
    if (bnrelu) {
#pragma unroll
        for (int c = 0; c < 8; ++c) {
            int o = f * 8 + c;
            float sc = bn_g[o] * rsqrtf(bn_v[o] + BN_EPS);
            r[c] = fmaxf(fmaf(r[c] - bn_m[o], sc, bn_b[o]), 0.f);
        }
    }
    if (outf) {
        outf[idx] = r;
    } else {
        outh[idx] = __builtin_convertvector(r, h8);
    }
}

// ---------------- Clenshaw prop, half4 gathers — small dims ----------------
__global__ void proph_kernel(const half4* __restrict__ feat, const half4* __restrict__ sub,
                             const half4* __restrict__ add, half4* __restrict__ outh,
                             f4* __restrict__ outf,
                             const int* __restrict__ row_ptr, const unsigned int* __restrict__ cw,
                             int n, int dim4, float scale, int has_sub,
                             int bnrelu, int used,
                             const float* __restrict__ bn_g, const float* __restrict__ bn_b,
                             const float* __restrict__ bn_m, const float* __restrict__ bn_v) {
    int idx = blockIdx.x * blockDim.x + threadIdx.x;
    if (idx >= n * dim4) return;
    int nd = idx / dim4;
    int f = idx - nd * dim4;
    int e0 = row_ptr[nd], e1 = row_ptr[nd + 1];
    f4 a0 = {0.f, 0.f, 0.f, 0.f}, a1 = a0, a2 = a0, a3 = a0;
    int e = e0;
    for (; e + 4 <= e1; e += 4) {
        unsigned int q0 = cw[e], q1 = cw[e + 1], q2 = cw[e + 2], q3 = cw[e + 3];
        f4 v0 = __builtin_convertvector(feat[(size_t)(q0 & 0x1FFFFu) * dim4 + f], f4);
        f4 v1 = __builtin_convertvector(feat[(size_t)(q1 & 0x1FFFFu) * dim4 + f], f4);
        f4 v2 = __builtin_convertvector(feat[(size_t)(q2 & 0x1FFFFu) * dim4 + f], f4);
        f4 v3 = __builtin_convertvector(feat[(size_t)(q3 & 0x1FFFFu) * dim4 + f], f4);
        a0 += wsrc(q0) * v0;
        a1 += wsrc(q1) * v1;
        a2 += wsrc(q2) * v2;
        a3 += wsrc(q3) * v3;
    }
    for (; e < e1; ++e) {
        unsigned int q = cw[e];
        a0 += wsrc(q) * __builtin_convertvector(feat[(size_t)(q & 0x1FFFFu) * dim4 + f], f4);
    }
    int degd = e1 - e0;
    float ms = (degd > 0) ? -scale * rsqrtf((float)degd) : 0.f;
    f4 r = ((a0 + a1) + (a2 + a3)) * ms;
    if (has_sub) r -= __builtin_convertvector(__builtin_nontemporal_load(&sub[idx]), f4);
    r += __builtin_convertvector(__builtin_nontemporal_load(&add[idx]), f4);
    if (bnrelu) {
#pragma unroll
        for (int c = 0; c < 4; ++c) {
            int o = f * 4 + c;
            if (o < used) {
                float sc = bn_g[o] * rsqrtf(bn_v[o] + BN_EPS);
                r[c] = fmaxf(fmaf(r[c] - bn_m[o], sc, bn_b[o]), 0.f);
            } else r[c] = 0.f;
        }
    }
    if (outf) {
        outf[idx] = r;
    } else {
        half4 h;
        h.x = (half1)r.x; h.y = (half1)r.y; h.z = (half1)r.z; h.w = (half1)r.w;
        outh[idx] = h;
    }
}

// layer-4 final: fp16 gathers/streams at stride 12 (dim4=3), fp32 out at stride 10
__global__ void propl_kernel(const half4* __restrict__ feat, const half4* __restrict__ sub,
                             const half4* __restrict__ add, float* __restrict__ out,
                             const int* __restrict__ row_ptr, const unsigned int* __restrict__ cw,
                             int n) {
    int idx = blockIdx.x * blockDim.x + threadIdx.x;
    if (idx >= n * 3) return;
    int nd = idx / 3;
    int f = idx - nd * 3;
    int e0 = row_ptr[nd], e1 = row_ptr[nd + 1];
    f4 a0 = {0.f, 0.f, 0.f, 0.f}, a1 = a0, a2 = a0, a3 = a0;
    int e = e0;
    for (; e + 4 <= e1; e += 4) {
        unsigned int q0 = cw[e], q1 = cw[e + 1], q2 = cw[e + 2], q3 = cw[e + 3];
        a0 += wsrc(q0) * __builtin_convertvector(feat[(size_t)(q0 & 0x1FFFFu) * 3 + f], f4);
        a1 += wsrc(q1) * __builtin_convertvector(feat[(size_t)(q1 & 0x1FFFFu) * 3 + f], f4);
        a2 += wsrc(q2) * __builtin_convertvector(feat[(size_t)(q2 & 0x1FFFFu) * 3 + f], f4);
        a3 += wsrc(q3) * __builtin_convertvector(feat[(size_t)(q3 & 0x1FFFFu) * 3 + f], f4);
    }
    for (; e < e1; ++e) {
        unsigned int q = cw[e];
        a0 += wsrc(q) * __builtin_convertvector(feat[(size_t)(q & 0x1FFFFu) * 3 + f], f4);
    }
    int degd = e1 - e0;
    float ms = (degd > 0) ? -rsqrtf((float)degd) : 0.f;
    f4 r = ((a0 + a1) + (a2 + a3)) * ms;
    r -= __builtin_convertvector(sub[idx], f4);
    r += __builtin_convertvector(add[idx], f4);
    int o = f * 4;
    float* orow = out + (size_t)nd * 10;
    if (o + 0 < 10) orow[o + 0] = r.x;
    if (o + 1 < 10) orow[o + 1] = r.y;
    if (o + 2 < 10) orow[o + 2] = r.z;
    if (o + 3 < 10) orow[o + 3] = r.w;
}

// ---------------- layer-1 GEMM via MFMA (8 waves = 8 k-slices, 64-node tile) --------
// Two sequential 32-node halves share one acc[2][4] (32 regs vs 64): total regs
// ~100/wave -> 2 blocks/CU (16 waves, ~50% occ) while keeping the 64-node block
// tile (Wt a[] reloaded per half from L1 — R7 lesson: don't shrink Wt amortization
// against HBM; here the reload is L1-resident). LSTR=68: 0 bank conflicts (R5).
#define LSTR 68
__global__ __launch_bounds__(512) void gemm_mfma_kernel(
        const half1* __restrict__ Xh, const half1* __restrict__ Wt,
        const float* __restrict__ bias, half1* __restrict__ CB, int n) {
    __shared__ half1 lds[8 * 32 * LSTR];  // 34816 B
    int lane = threadIdx.x & 63;
    int ks = threadIdx.x >> 6;   // 0..7
    int m16 = lane & 15;
    int quad = lane >> 4;
    int ntile = blockIdx.x * 64;

    half1* slab = lds + (size_t)ks * 32 * LSTR;
    int nl0 = lane >> 3;    // 0..7
    int chunk = lane & 7;   // 0..7, 16B each

#pragma unroll
    for (int hh = 0; hh < 2; ++hh) {
        f4 acc[2][4];
#pragma unroll
        for (int nt = 0; nt < 2; ++nt)
#pragma unroll
            for (int i = 0; i < 4; ++i) acc[nt][i] = (f4){0.f, 0.f, 0.f, 0.f};

#pragma unroll
        for (int kc = 0; kc < 4; ++kc) {
            int koff = kc * 32 + quad * 8;
            h8 a[4];
#pragma unroll
            for (int i = 0; i < 4; ++i)
                a[i] = *(const h8*)(Wt + (size_t)(ks * 64 + i * 16 + m16) * 128 + koff);
            h8 b[2];
#pragma unroll
            for (int nt = 0; nt < 2; ++nt) {
                int node = min(ntile + hh * 32 + nt * 16 + m16, n - 1);
                b[nt] = *(const h8*)(Xh + (size_t)node * 128 + koff);
            }
#pragma unroll
            for (int nt = 0; nt < 2; ++nt)
#pragma unroll
                for (int i = 0; i < 4; ++i)
                    acc[nt][i] = __builtin_amdgcn_mfma_f32_16x16x32_f16(a[i], b[nt], acc[nt][i], 0, 0, 0);
        }

        // stage this half's 32 nodes into the wave-private slab
#pragma unroll
        for (int p = 0; p < 2; ++p) {
            int node_l = p * 16 + m16;
#pragma unroll
            for (int i = 0; i < 4; ++i) {
                int ob = i * 16 + quad * 4;
                f4 v = acc[p][i];
                if (ks == 0) {
                    const f4 b4 = *(const f4*)(bias + ob);
                    v += b4;
                }
                half4 h;
                h.x = (half1)v[0]; h.y = (half1)v[1]; h.z = (half1)v[2]; h.w = (half1)v[3];
                *(half4*)(slab + node_l * LSTR + ob) = h;
            }
        }
        asm volatile("s_waitcnt lgkmcnt(0)" ::: "memory");  // cross-lane RAW within wave
        // coalesced copy-out: 8 lanes per 128B node row
#pragma unroll
        for (int j = 0; j < 4; ++j) {
            int node_l = j * 8 + nl0;
            int node = ntile + hh * 32 + node_l;
            if (node < n) {
                h8 v = *(const h8*)(slab + node_l * LSTR + chunk * 8);
                *(h8*)(CB + ((size_t)ks * n + node) * 64 + chunk * 8) = v;
            }
        }
        // DS ops in-order per wave: hh=1 restage cannot pass the reads above.
    }
}

// ---------------- small-layer GEMM: block = KK waves, wave k, lane = node -------------
template <int KK, int DIN4, int NACC>
__global__ void gemm_smallw_kernel(const float* __restrict__ X, const float* __restrict__ Wp,
                                   const float* __restrict__ bias, int dout,
                                   half4* __restrict__ CB, int n) {
    int lane = threadIdx.x & 63;
    int k = __builtin_amdgcn_readfirstlane((int)(threadIdx.x >> 6));
    int node0 = blockIdx.x * 64 + lane;
    int node = min(node0, n - 1);
    f4 acc[NACC];
#pragma unroll
    for (int i = 0; i < NACC; ++i) {
        f4 v = {0.f, 0.f, 0.f, 0.f};
        if (k == 0 && bias) {
#pragma unroll
            for (int c = 0; c < 4; ++c) {
                int o = i * 4 + c;
                v[c] = (o < dout) ? bias[o] : 0.f;
            }
        }
        acc[i] = v;
    }
    const f4* Xr = (const f4*)(X + (size_t)node * (DIN4 * 4));
    const f4* Wk = (const f4*)(Wp + (size_t)k * (DIN4 * 4) * (NACC * 4));
    for (int d4 = 0; d4 < DIN4; ++d4) {
        f4 xv = Xr[d4];
#pragma unroll
        for (int j = 0; j < 4; ++j) {
            float xs = xv[j];
#pragma unroll
            for (int i = 0; i < NACC; ++i)
                acc[i] += xs * Wk[(d4 * 4 + j) * NACC + i];
        }
    }
    if (node0 < n) {
        size_t base = ((size_t)k * n + node) * NACC;
#pragma unroll
        for (int i = 0; i < NACC; ++i) {
            half4 h;
            h.x = (half1)acc[i].x; h.y = (half1)acc[i].y;
            h.z = (half1)acc[i].z; h.w = (half1)acc[i].w;
            CB[base + i] = h;
        }
    }
}

// ---------------- host driver ----------------

extern "C" void kernel_launch(void* const* d_in, const int* in_sizes, int n_in,
                              void* d_out, int out_size, void* d_ws, size_t ws_size,
                              hipStream_t stream) {
    const float* x  = (const float*)d_in[0];
    const int*   ei = (const int*)d_in[1];
    const float* Wl[4] = {(const float*)d_in[2], (const float*)d_in[4],
                          (const float*)d_in[6], (const float*)d_in[8]};
    const float* bl[4] = {(const float*)d_in[3], (const float*)d_in[5],
                          (const float*)d_in[7], (const float*)d_in[9]};
    const float* bn[3][4];
    for (int l = 0; l < 3; ++l)
        for (int j = 0; j < 4; ++j)
            bn[l][j] = (const float*)d_in[10 + 4 * l + j];

    char* ws = (char*)d_ws;
    size_t off = 0;
    auto alloc = [&](size_t bytes) -> void* {
        void* p = (void*)(ws + off);
        off = (off + bytes + 255) & ~(size_t)255;
        return p;
    };
    int*   deg      = (int*)alloc(NN * 4);
    int*   row_ptr  = (int*)alloc((NN + 1) * 4);
    int*   bstart   = (int*)alloc((NBUCK + 1) * 4);
    unsigned int* cw = (unsigned int*)alloc((size_t)NE * 4);
    half1* CB1h    = (half1*)alloc((size_t)8 * NN * 64 * 2);
    half1* CBsh    = (half1*)alloc((size_t)6 * NN * 20 * 2);
    half1* S0      = (half1*)alloc((size_t)NN * 64 * 2);
    half1* S1      = (half1*)alloc((size_t)NN * 64 * 2);
    half1* S2      = (half1*)alloc((size_t)NN * 64 * 2);
    float* H1f     = (float*)alloc((size_t)NN * 64 * 4);
    float* H2f     = (float*)alloc((size_t)NN * 20 * 4);
    float* H3f     = (float*)alloc((size_t)NN * 12 * 4);
    float* Wp2     = (float*)alloc((size_t)6 * 64 * 20 * 4);
    float* Wp3     = (float*)alloc((size_t)4 * 20 * 12 * 4);
    float* Wp4     = (float*)alloc((size_t)4 * 12 * 12 * 4);
    half1* Xh      = (half1*)alloc((size_t)NN * 128 * 2);
    half1* Wt1     = (half1*)alloc((size_t)512 * 128 * 2);

    // CSR-build scratch aliased into CB1h (consumed before gemm_mfma writes it):
    unsigned int* tmp = (unsigned int*)CB1h;                // 6.4 MB
    int* hist_g = (int*)((char*)CB1h + (16u << 20));        // NC*NBUCK*4 = 600 KB
    int* off_g  = hist_g + NC * NBUCK;                      // 600 KB

    const int* srcp = ei;
    const int* dstp = ei + NE;
    const int NB = divup(NN, 64);

    histb_kernel<<<NC, 256, 0, stream>>>(dstp, hist_g);
    bscan1_kernel<<<1, 1024, 0, stream>>>(hist_g, bstart, row_ptr);
    boff_kernel<<<divup(NBUCK, 256), 256, 0, stream>>>(bstart, hist_g, off_g);
    binscatter_kernel<<<NC * 8, 256, 0, stream>>>(srcp, dstp, off_g, tmp);
    finalize_kernel<<<NBUCK, 256, 0, stream>>>(tmp, bstart, row_ptr, deg, cw);
    packdeg_kernel<<<divup(NE, 256), 256, 0, stream>>>(cw, deg);

    cvtx_kernel<<<divup(NN * 32, 256), 256, 0, stream>>>((const float4*)x, (half4*)Xh, NN * 32);
    transw_kernel<<<divup(512 * 128, 256), 256, 0, stream>>>(Wl[0], Wt1);
    padw_kernel<<<divup(6 * 64 * 20, 256), 256, 0, stream>>>(Wl[1], Wp2, 6, 64, 18, 64, 20);
    padw_kernel<<<divup(4 * 20 * 12, 256), 256, 0, stream>>>(Wl[2], Wp3, 4, 18, 9, 20, 12);
    padw_kernel<<<divup(4 * 12 * 12, 256), 256, 0, stream>>>(Wl[3], Wp4, 4, 9, 10, 12, 12);

    // dim-64 prop (h8 gathers)
    auto prop1 = [&](const half1* feat, const half1* sub, const half1* add,
                     half1* outh, float* outf, float scale, int bnrelu,
                     const float* g, const float* bb, const float* m, const float* v) {
        proph8_kernel<<<divup(NN * 8, 256), 256, 0, stream>>>(
            (const h8*)feat, (const h8*)sub, (const h8*)add,
            (h8*)outh, (f8*)outf, row_ptr, cw, NN, scale,
            sub != nullptr, bnrelu, g, bb, m, v);
    };
    // small-dim prop (half4 gathers)
    auto prop = [&](const half1* feat, const half1* sub, const half1* add,
                    half1* outh, float* outf, int dim4, float scale,
                    int bnrelu, int used, const float* g, const float* bb,
                    const float* m, const float* v) {
        proph_kernel<<<divup(NN * dim4, 256), 256, 0, stream>>>(
            (const half4*)feat, (const half4*)sub, (const half4*)add,
            (half4*)outh, (f4*)outf, row_ptr, cw, NN, dim4, scale,
            sub != nullptr, bnrelu, used, g, bb, m, v);
    };

    // ---- layer 1 (din=128, dout=64, K=8) -> H1f ----
    gemm_mfma_kernel<<<NB, 512, 0, stream>>>(Xh, Wt1, bl[0], CB1h, NN);
    {
        auto C = [&](int k) { return (const half1*)(CB1h + (size_t)k * NN * 64); };
        prop1(C(7), nullptr, C(6), S0, nullptr, 2.f, 0, 0, 0, 0, 0);
        prop1(S0, C(7), C(5), S1, nullptr, 2.f, 0, 0, 0, 0, 0);
        prop1(S1, S0, C(4), S2, nullptr, 2.f, 0, 0, 0, 0, 0);
        prop1(S2, S1, C(3), S0, nullptr, 2.f, 0, 0, 0, 0, 0);
        prop1(S0, S2, C(2), S1, nullptr, 2.f, 0, 0, 0, 0, 0);
        prop1(S1, S0, C(1), S2, nullptr, 2.f, 0, 0, 0, 0, 0);
        prop1(S2, S1, C(0), nullptr, H1f, 1.f, 1,
              bn[0][0], bn[0][1], bn[0][2], bn[0][3]);
    }

    // ---- layer 2 (din=64, dout=18 pad 20, K=6): X=H1f -> H2f ----
    gemm_smallw_kernel<6, 16, 5><<<NB, 384, 0, stream>>>(H1f, Wp2, bl[1], 18,
                                                         (half4*)CBsh, NN);
    {
        auto C = [&](int k) { return (const half1*)(CBsh + (size_t)k * NN * 20); };
        prop(C(5), nullptr, C(4), S0, nullptr, 5, 2.f, 0, 18, 0, 0, 0, 0);
        prop(S0, C(5), C(3), S1, nullptr, 5, 2.f, 0, 18, 0, 0, 0, 0);
        prop(S1, S0, C(2), S2, nullptr, 5, 2.f, 0, 18, 0, 0, 0, 0);
        prop(S2, S1, C(1), S0, nullptr, 5, 2.f, 0, 18, 0, 0, 0, 0);
        prop(S0, S2, C(0), nullptr, H2f, 5, 1.f, 1, 18,
             bn[1][0], bn[1][1], bn[1][2], bn[1][3]);
    }

    // ---- layer 3 (din=18 str20, dout=9 pad 12, K=4): X=H2f -> H3f ----
    gemm_smallw_kernel<4, 5, 3><<<NB, 256, 0, stream>>>(H2f, Wp3, bl[2], 9,
                                                        (half4*)CBsh, NN);
    {
        auto C = [&](int k) { return (const half1*)(CBsh + (size_t)k * NN * 12); };
        prop(C(3), nullptr, C(2), S0, nullptr, 3, 2.f, 0, 9, 0, 0, 0, 0);
        prop(S0, C(3), C(1), S1, nullptr, 3, 2.f, 0, 9, 0, 0, 0, 0);
        prop(S1, S0, C(0), nullptr, H3f, 3, 1.f, 1, 9,
             bn[2][0], bn[2][1], bn[2][2], bn[2][3]);
    }

    // ---- layer 4 (din=9 str12, dout=10 pad 12, K=4): X=H3f -> d_out ----
    gemm_smallw_kernel<4, 3, 3><<<NB, 256, 0, stream>>>(H3f, Wp4, bl[3], 10,
                                                        (half4*)CBsh, NN);
    {
        auto C = [&](int k) { return (const half1*)(CBsh + (size_t)k * NN * 12); };
        prop(C(3), nullptr, C(2), S0, nullptr, 3, 2.f, 0, 10, 0, 0, 0, 0);
        prop(S0, C(3), C(1), S1, nullptr, 3, 2.f, 0, 10, 0, 0, 0, 0);
        propl_kernel<<<divup(NN * 3, 256), 256, 0, stream>>>(
            (const half4*)S1, (const half4*)S0, (const half4*)CBsh,
            (float*)d_out, row_ptr, cw, NN);
    }
}

// Round 13
// 753.422 us; speedup vs baseline: 1.5021x; 1.0164x over previous
//
#include <hip/hip_runtime.h>

#define NN 100000
#define NE 1600000
#define BN_EPS 1e-5f

// CSR binning parameters
#define BSH 7
#define BSZ (1 << BSH)   // 128 dsts per bucket
#define NBUCK 782        // divup(NN, BSZ)
#define NC 192           // edge chunks
#define CE 8334          // divup(NE, NC)

typedef _Float16 half1;
typedef _Float16 half4 __attribute__((ext_vector_type(4)));
typedef _Float16 h8 __attribute__((ext_vector_type(8)));
typedef float f4 __attribute__((ext_vector_type(4)));
typedef float f8 __attribute__((ext_vector_type(8)));

static inline int divup(int a, int b) { return (a + b - 1) / b; }

// per-edge source weight from packed entry: src in [0:17), deg_src in [17:32)
__device__ __forceinline__ float wsrc(unsigned int q) {
    unsigned int dg = q >> 17;
    return dg ? rsqrtf((float)dg) : 0.f;
}

// ---------------- preprocessing (no global atomics) ----------------

__global__ void histb_kernel(const int* __restrict__ dst, int* __restrict__ hist_g) {
    __shared__ int h[NBUCK];
    int c = blockIdx.x;
    for (int i = threadIdx.x; i < NBUCK; i += blockDim.x) h[i] = 0;
    __syncthreads();
    int e0 = c * CE, e1 = min(e0 + CE, NE);
    for (int e = e0 + threadIdx.x; e < e1; e += blockDim.x)
        atomicAdd(&h[dst[e] >> BSH], 1);
    __syncthreads();
    for (int i = threadIdx.x; i < NBUCK; i += blockDim.x) hist_g[c * NBUCK + i] = h[i];
}

__global__ void bscan1_kernel(const int* __restrict__ hist_g, int* __restrict__ bucket_start,
                              int* __restrict__ row_ptr) {
    __shared__ int sh[1024];
    int t = threadIdx.x;
    int tot = 0;
    if (t < NBUCK)
        for (int c = 0; c < NC; ++c) tot += hist_g[c * NBUCK + t];
    sh[t] = (t < NBUCK) ? tot : 0;
    __syncthreads();
    for (int off = 1; off < 1024; off <<= 1) {
        int v = (t >= off) ? sh[t - off] : 0;
        __syncthreads();
        sh[t] += v;
        __syncthreads();
    }
    if (t < NBUCK) bucket_start[t] = sh[t] - tot;
    if (t == 0) { bucket_start[NBUCK] = NE; row_ptr[NN] = NE; }
}

__global__ void boff_kernel(const int* __restrict__ bucket_start, const int* __restrict__ hist_g,
                            int* __restrict__ off_g) {
    int b = blockIdx.x * blockDim.x + threadIdx.x;
    if (b >= NBUCK) return;
    int run = bucket_start[b];
#pragma unroll 4
    for (int c = 0; c < NC; ++c) {
        off_g[c * NBUCK + b] = run;
        run += hist_g[c * NBUCK + b];
    }
}

__global__ void binscatter_kernel(const int* __restrict__ src, const int* __restrict__ dst,
                                  const int* __restrict__ off_g, unsigned int* __restrict__ tmp) {
    __shared__ int off_l[NBUCK];
    int myx = blockIdx.x & 7;
    int c = blockIdx.x >> 3;
    for (int i = threadIdx.x; i < NBUCK; i += blockDim.x)
        off_l[i] = ((i & 7) == myx) ? off_g[c * NBUCK + i] : 0;
    __syncthreads();
    int e0 = c * CE, e1 = min(e0 + CE, NE);
    for (int e = e0 + threadIdx.x; e < e1; e += blockDim.x) {
        int d = dst[e];
        int b = d >> BSH;
        if ((b & 7) != myx) continue;
        int s = src[e];
        int pos = atomicAdd(&off_l[b], 1);
        tmp[pos] = (unsigned int)s | ((unsigned int)(d & (BSZ - 1)) << 25);
    }
}

__global__ void finalize_kernel(const unsigned int* __restrict__ tmp,
                                const int* __restrict__ bucket_start,
                                int* __restrict__ row_ptr, int* __restrict__ deg,
                                unsigned int* __restrict__ cw) {
    __shared__ int cnt[BSZ], sc[BSZ], cur[BSZ];
    int b = blockIdx.x, t = threadIdx.x;
    int e0 = bucket_start[b], e1 = bucket_start[b + 1];
    if (t < BSZ) cnt[t] = 0;
    __syncthreads();
    for (int e = e0 + t; e < e1; e += blockDim.x) atomicAdd(&cnt[tmp[e] >> 25], 1);
    __syncthreads();
    if (t < BSZ) sc[t] = cnt[t];
    __syncthreads();
    for (int off = 1; off < BSZ; off <<= 1) {
        int v = (t >= off && t < BSZ) ? sc[t - off] : 0;
        __syncthreads();
        if (t < BSZ) sc[t] += v;
        __syncthreads();
    }
    if (t < BSZ) {
        int p = e0 + sc[t] - cnt[t];
        cur[t] = p;
        int nd = (b << BSH) + t;
        if (nd < NN) { row_ptr[nd] = p; deg[nd] = cnt[t]; }
    }
    __syncthreads();
    for (int e = e0 + t; e < e1; e += blockDim.x) {
        unsigned int r = tmp[e];
        int ld = r >> 25;
        int k = atomicAdd(&cur[ld], 1);
        cw[k] = r & 0x1FFFFu;
    }
}

__global__ void packdeg_kernel(unsigned int* __restrict__ cw, const int* __restrict__ deg) {
    int e = blockIdx.x * blockDim.x + threadIdx.x;
    if (e >= NE) return;
    unsigned int q = cw[e];
    int dg = deg[q];
    if (dg > 32767) dg = 32767;
    cw[e] = q | ((unsigned int)dg << 17);
}

// ---------------- fp16 converts for MFMA ----------------

__global__ void cvtx_kernel(const float4* __restrict__ X, half4* __restrict__ Xh, int tot4) {
    int i = blockIdx.x * blockDim.x + threadIdx.x;
    if (i >= tot4) return;
    float4 v = X[i];
    half4 h;
    h.x = (half1)v.x; h.y = (half1)v.y; h.z = (half1)v.z; h.w = (half1)v.w;
    Xh[i] = h;
}

// ---------------- unified weight prep (transw + 3x padw in one launch) -------------
// ranges: [0, 65536)            : Wt[og][kd] = W1[og>>6][kd][og&63] fp16
//         [65536, 65536+7680)   : Wp2 pad (6,64->64,18->20)
//         [+7680, +7680+960)    : Wp3 pad (4,18->20,9->12)
//         [+960, +960+576)      : Wp4 pad (4,9->12,10->12)
__device__ __forceinline__ void padw_one(const float* __restrict__ src, float* __restrict__ dst,
                                         int i, int dins, int douts, int dind, int doutd) {
    int o = i % doutd;
    int r = i / doutd;
    int dd = r % dind;
    int k = r / dind;
    dst[i] = (dd < dins && o < douts) ? src[((size_t)k * dins + dd) * douts + o] : 0.f;
}

__global__ void prepw_kernel(const float* __restrict__ W1, half1* __restrict__ Wt,
                             const float* __restrict__ W2, float* __restrict__ Wp2,
                             const float* __restrict__ W3, float* __restrict__ Wp3,
                             const float* __restrict__ W4, float* __restrict__ Wp4) {
    int i = blockIdx.x * blockDim.x + threadIdx.x;
    if (i < 65536) {
        int kd = i >> 9;
        int og = i & 511;
        int k = og >> 6, o = og & 63;
        Wt[(size_t)og * 128 + kd] = (half1)W1[((size_t)k * 128 + kd) * 64 + o];
        return;
    }
    i -= 65536;
    if (i < 7680) { padw_one(W2, Wp2, i, 64, 18, 64, 20); return; }
    i -= 7680;
    if (i < 960) { padw_one(W3, Wp3, i, 18, 9, 20, 12); return; }
    i -= 960;
    if (i < 576) { padw_one(W4, Wp4, i, 9, 10, 12, 12); return; }
}

// ---------------- Clenshaw prop, h8 (16B) gathers — dim == 64 ----------------
// R9 form: 2 accumulators, scalar cw loads (broadcast-served across the 8
// f-lanes of a node); sub/add nontemporal (read-once streams).
__global__ void proph8_kernel(const h8* __restrict__ feat, const h8* __restrict__ sub,
                              const h8* __restrict__ add, h8* __restrict__ outh,
                              f8* __restrict__ outf,
                              const int* __restrict__ row_ptr, const unsigned int* __restrict__ cw,
                              int n, float scale, int has_sub, int bnrelu,
                              const float* __restrict__ bn_g, const float* __restrict__ bn_b,
                              const float* __restrict__ bn_m, const float* __restrict__ bn_v) {
    int idx = blockIdx.x * blockDim.x + threadIdx.x;
    if (idx >= n * 8) return;
    int nd = idx >> 3;
    int f = idx & 7;
    int e0 = row_ptr[nd], e1 = row_ptr[nd + 1];
    f8 a0 = {0.f, 0.f, 0.f, 0.f, 0.f, 0.f, 0.f, 0.f}, a1 = a0;
    int e = e0;
    for (; e + 4 <= e1; e += 4) {
        unsigned int q0 = cw[e], q1 = cw[e + 1], q2 = cw[e + 2], q3 = cw[e + 3];
        h8 h0 = feat[(size_t)(q0 & 0x1FFFFu) * 8 + f];
        h8 h1 = feat[(size_t)(q1 & 0x1FFFFu) * 8 + f];
        h8 h2 = feat[(size_t)(q2 & 0x1FFFFu) * 8 + f];
        h8 h3 = feat[(size_t)(q3 & 0x1FFFFu) * 8 + f];
        a0 += wsrc(q0) * __builtin_convertvector(h0, f8);
        a1 += wsrc(q1) * __builtin_convertvector(h1, f8);
        a0 += wsrc(q2) * __builtin_convertvector(h2, f8);
        a1 += wsrc(q3) * __builtin_convertvector(h3, f8);
    }
    for (; e < e1; ++e) {
        unsigned int q = cw[e];
        a0 += wsrc(q) * __builtin_convertvector(feat[(size_t)(q & 0x1FFFFu) * 8 + f], f8);
    }
    int degd = e1 - e0;
    float ms = (degd > 0) ? -scale * rsqrtf((float)degd) : 0.f;
    f8 r = (a0 + a1) * ms;
    if (has_sub) r -= __builtin_convertvector(__builtin_nontemporal_load(&sub[idx]), f8);
    r += __builtin_convertvector(__builtin_nontemporal_load(&add[idx]), f8);
    if (bnrelu) {
#pragma unroll
        for (int c = 0; c < 8; ++c) {
            int o = f * 8 + c;
            float sc = bn_g[o] * rsqrtf(bn_v[o] + BN_EPS);
            r[c] = fmaxf(fmaf(r[c] - bn_m[o], sc, bn_b[o]), 0.f);
        }
    }
    if (outf) {
        outf[idx] = r;
    } else {
        outh[idx] = __builtin_convertvector(r, h8);
    }
}

// ---------------- Clenshaw prop, half4 gathers — small dims ----------------
__global__ void proph_kernel(const half4* __restrict__ feat, const half4* __restrict__ sub,
                             const half4* __restrict__ add, half4* __restrict__ outh,
                             f4* __restrict__ outf,
                             const int* __restrict__ row_ptr, const unsigned int* __restrict__ cw,
                             int n, int dim4, float scale, int has_sub,
                             int bnrelu, int used,
                             const float* __restrict__ bn_g, const float* __restrict__ bn_b,
                             const float* __restrict__ bn_m, const float* __restrict__ bn_v) {
    int idx = blockIdx.x * blockDim.x + threadIdx.x;
    if (idx >= n * dim4) return;
    int nd = idx / dim4;
    int f = idx - nd * dim4;
    int e0 = row_ptr[nd], e1 = row_ptr[nd + 1];
    f4 a0 = {0.f, 0.f, 0.f, 0.f}, a1 = a0, a2 = a0, a3 = a0;
    int e = e0;
    for (; e + 4 <= e1; e += 4) {
        unsigned int q0 = cw[e], q1 = cw[e + 1], q2 = cw[e + 2], q3 = cw[e + 3];
        f4 v0 = __builtin_convertvector(feat[(size_t)(q0 & 0x1FFFFu) * dim4 + f], f4);
        f4 v1 = __builtin_convertvector(feat[(size_t)(q1 & 0x1FFFFu) * dim4 + f], f4);
        f4 v2 = __builtin_convertvector(feat[(size_t)(q2 & 0x1FFFFu) * dim4 + f], f4);
        f4 v3 = __builtin_convertvector(feat[(size_t)(q3 & 0x1FFFFu) * dim4 + f], f4);
        a0 += wsrc(q0) * v0;
        a1 += wsrc(q1) * v1;
        a2 += wsrc(q2) * v2;
        a3 += wsrc(q3) * v3;
    }
    for (; e < e1; ++e) {
        unsigned int q = cw[e];
        a0 += wsrc(q) * __builtin_convertvector(feat[(size_t)(q & 0x1FFFFu) * dim4 + f], f4);
    }
    int degd = e1 - e0;
    float ms = (degd > 0) ? -scale * rsqrtf((float)degd) : 0.f;
    f4 r = ((a0 + a1) + (a2 + a3)) * ms;
    if (has_sub) r -= __builtin_convertvector(__builtin_nontemporal_load(&sub[idx]), f4);
    r += __builtin_convertvector(__builtin_nontemporal_load(&add[idx]), f4);
    if (bnrelu) {
#pragma unroll
        for (int c = 0; c < 4; ++c) {
            int o = f * 4 + c;
            if (o < used) {
                float sc = bn_g[o] * rsqrtf(bn_v[o] + BN_EPS);
                r[c] = fmaxf(fmaf(r[c] - bn_m[o], sc, bn_b[o]), 0.f);
            } else r[c] = 0.f;
        }
    }
    if (outf) {
        outf[idx] = r;
    } else {
        half4 h;
        h.x = (half1)r.x; h.y = (half1)r.y; h.z = (half1)r.z; h.w = (half1)r.w;
        outh[idx] = h;
    }
}

// layer-4 final: fp16 gathers/streams at stride 12 (dim4=3), fp32 out at stride 10
__global__ void propl_kernel(const half4* __restrict__ feat, const half4* __restrict__ sub,
                             const half4* __restrict__ add, float* __restrict__ out,
                             const int* __restrict__ row_ptr, const unsigned int* __restrict__ cw,
                             int n) {
    int idx = blockIdx.x * blockDim.x + threadIdx.x;
    if (idx >= n * 3) return;
    int nd = idx / 3;
    int f = idx - nd * 3;
    int e0 = row_ptr[nd], e1 = row_ptr[nd + 1];
    f4 a0 = {0.f, 0.f, 0.f, 0.f}, a1 = a0, a2 = a0, a3 = a0;
    int e = e0;
    for (; e + 4 <= e1; e += 4) {
        unsigned int q0 = cw[e], q1 = cw[e + 1], q2 = cw[e + 2], q3 = cw[e + 3];
        a0 += wsrc(q0) * __builtin_convertvector(feat[(size_t)(q0 & 0x1FFFFu) * 3 + f], f4);
        a1 += wsrc(q1) * __builtin_convertvector(feat[(size_t)(q1 & 0x1FFFFu) * 3 + f], f4);
        a2 += wsrc(q2) * __builtin_convertvector(feat[(size_t)(q2 & 0x1FFFFu) * 3 + f], f4);
        a3 += wsrc(q3) * __builtin_convertvector(feat[(size_t)(q3 & 0x1FFFFu) * 3 + f], f4);
    }
    for (; e < e1; ++e) {
        unsigned int q = cw[e];
        a0 += wsrc(q) * __builtin_convertvector(feat[(size_t)(q & 0x1FFFFu) * 3 + f], f4);
    }
    int degd = e1 - e0;
    float ms = (degd > 0) ? -rsqrtf((float)degd) : 0.f;
    f4 r = ((a0 + a1) + (a2 + a3)) * ms;
    r -= __builtin_convertvector(sub[idx], f4);
    r += __builtin_convertvector(add[idx], f4);
    int o = f * 4;
    float* orow = out + (size_t)nd * 10;
    if (o + 0 < 10) orow[o + 0] = r.x;
    if (o + 1 < 10) orow[o + 1] = r.y;
    if (o + 2 < 10) orow[o + 2] = r.z;
    if (o + 3 < 10) orow[o + 3] = r.w;
}

// ---------------- layer-1 GEMM via MFMA (8 waves = 8 k-slices, 64-node tile) --------
// R12 form (verified 66us, occ 27-30%, 0 conflicts): two sequential 32-node halves
// share one acc[2][4]; Wt a[] reloaded per half from L1; LSTR=68 LDS slab epilogue.
#define LSTR 68
__global__ __launch_bounds__(512) void gemm_mfma_kernel(
        const half1* __restrict__ Xh, const half1* __restrict__ Wt,
        const float* __restrict__ bias, half1* __restrict__ CB, int n) {
    __shared__ half1 lds[8 * 32 * LSTR];  // 34816 B
    int lane = threadIdx.x & 63;
    int ks = threadIdx.x >> 6;   // 0..7
    int m16 = lane & 15;
    int quad = lane >> 4;
    int ntile = blockIdx.x * 64;

    half1* slab = lds + (size_t)ks * 32 * LSTR;
    int nl0 = lane >> 3;    // 0..7
    int chunk = lane & 7;   // 0..7, 16B each

#pragma unroll
    for (int hh = 0; hh < 2; ++hh) {
        f4 acc[2][4];
#pragma unroll
        for (int nt = 0; nt < 2; ++nt)
#pragma unroll
            for (int i = 0; i < 4; ++i) acc[nt][i] = (f4){0.f, 0.f, 0.f, 0.f};

#pragma unroll
        for (int kc = 0; kc < 4; ++kc) {
            int koff = kc * 32 + quad * 8;
            h8 a[4];
#pragma unroll
            for (int i = 0; i < 4; ++i)
                a[i] = *(const h8*)(Wt + (size_t)(ks * 64 + i * 16 + m16) * 128 + koff);
            h8 b[2];
#pragma unroll
            for (int nt = 0; nt < 2; ++nt) {
                int node = min(ntile + hh * 32 + nt * 16 + m16, n - 1);
                b[nt] = *(const h8*)(Xh + (size_t)node * 128 + koff);
            }
#pragma unroll
            for (int nt = 0; nt < 2; ++nt)
#pragma unroll
                for (int i = 0; i < 4; ++i)
                    acc[nt][i] = __builtin_amdgcn_mfma_f32_16x16x32_f16(a[i], b[nt], acc[nt][i], 0, 0, 0);
        }

        // stage this half's 32 nodes into the wave-private slab
#pragma unroll
        for (int p = 0; p < 2; ++p) {
            int node_l = p * 16 + m16;
#pragma unroll
            for (int i = 0; i < 4; ++i) {
                int ob = i * 16 + quad * 4;
                f4 v = acc[p][i];
                if (ks == 0) {
                    const f4 b4 = *(const f4*)(bias + ob);
                    v += b4;
                }
                half4 h;
                h.x = (half1)v[0]; h.y = (half1)v[1]; h.z = (half1)v[2]; h.w = (half1)v[3];
                *(half4*)(slab + node_l * LSTR + ob) = h;
            }
        }
        asm volatile("s_waitcnt lgkmcnt(0)" ::: "memory");  // cross-lane RAW within wave
        // coalesced copy-out: 8 lanes per 128B node row
#pragma unroll
        for (int j = 0; j < 4; ++j) {
            int node_l = j * 8 + nl0;
            int node = ntile + hh * 32 + node_l;
            if (node < n) {
                h8 v = *(const h8*)(slab + node_l * LSTR + chunk * 8);
                *(h8*)(CB + ((size_t)ks * n + node) * 64 + chunk * 8) = v;
            }
        }
        // DS ops in-order per wave: hh=1 restage cannot pass the reads above.
    }
}

// ---------------- small-layer GEMM: block = KK waves, wave k, lane = node -------------
template <int KK, int DIN4, int NACC>
__global__ void gemm_smallw_kernel(const float* __restrict__ X, const float* __restrict__ Wp,
                                   const float* __restrict__ bias, int dout,
                                   half4* __restrict__ CB, int n) {
    int lane = threadIdx.x & 63;
    int k = __builtin_amdgcn_readfirstlane((int)(threadIdx.x >> 6));
    int node0 = blockIdx.x * 64 + lane;
    int node = min(node0, n - 1);
    f4 acc[NACC];
#pragma unroll
    for (int i = 0; i < NACC; ++i) {
        f4 v = {0.f, 0.f, 0.f, 0.f};
        if (k == 0 && bias) {
#pragma unroll
            for (int c = 0; c < 4; ++c) {
                int o = i * 4 + c;
                v[c] = (o < dout) ? bias[o] : 0.f;
            }
        }
        acc[i] = v;
    }
    const f4* Xr = (const f4*)(X + (size_t)node * (DIN4 * 4));
    const f4* Wk = (const f4*)(Wp + (size_t)k * (DIN4 * 4) * (NACC * 4));
    for (int d4 = 0; d4 < DIN4; ++d4) {
        f4 xv = Xr[d4];
#pragma unroll
        for (int j = 0; j < 4; ++j) {
            float xs = xv[j];
#pragma unroll
            for (int i = 0; i < NACC; ++i)
                acc[i] += xs * Wk[(d4 * 4 + j) * NACC + i];
        }
    }
    if (node0 < n) {
        size_t base = ((size_t)k * n + node) * NACC;
#pragma unroll
        for (int i = 0; i < NACC; ++i) {
            half4 h;
            h.x = (half1)acc[i].x; h.y = (half1)acc[i].y;
            h.z = (half1)acc[i].z; h.w = (half1)acc[i].w;
            CB[base + i] = h;
        }
    }
}

// ---------------- host driver ----------------

extern "C" void kernel_launch(void* const* d_in, const int* in_sizes, int n_in,
                              void* d_out, int out_size, void* d_ws, size_t ws_size,
                              hipStream_t stream) {
    const float* x  = (const float*)d_in[0];
    const int*   ei = (const int*)d_in[1];
    const float* Wl[4] = {(const float*)d_in[2], (const float*)d_in[4],
                          (const float*)d_in[6], (const float*)d_in[8]};
    const float* bl[4] = {(const float*)d_in[3], (const float*)d_in[5],
                          (const float*)d_in[7], (const float*)d_in[9]};
    const float* bn[3][4];
    for (int l = 0; l < 3; ++l)
        for (int j = 0; j < 4; ++j)
            bn[l][j] = (const float*)d_in[10 + 4 * l + j];

    char* ws = (char*)d_ws;
    size_t off = 0;
    auto alloc = [&](size_t bytes) -> void* {
        void* p = (void*)(ws + off);
        off = (off + bytes + 255) & ~(size_t)255;
        return p;
    };
    int*   deg      = (int*)alloc(NN * 4);
    int*   row_ptr  = (int*)alloc((NN + 1) * 4);
    int*   bstart   = (int*)alloc((NBUCK + 1) * 4);
    unsigned int* cw = (unsigned int*)alloc((size_t)NE * 4);
    half1* CB1h    = (half1*)alloc((size_t)8 * NN * 64 * 2);
    half1* CBsh    = (half1*)alloc((size_t)6 * NN * 20 * 2);
    half1* S0      = (half1*)alloc((size_t)NN * 64 * 2);
    half1* S1      = (half1*)alloc((size_t)NN * 64 * 2);
    half1* S2      = (half1*)alloc((size_t)NN * 64 * 2);
    float* H1f     = (float*)alloc((size_t)NN * 64 * 4);
    float* H2f     = (float*)alloc((size_t)NN * 20 * 4);
    float* H3f     = (float*)alloc((size_t)NN * 12 * 4);
    float* Wp2     = (float*)alloc((size_t)6 * 64 * 20 * 4);
    float* Wp3     = (float*)alloc((size_t)4 * 20 * 12 * 4);
    float* Wp4     = (float*)alloc((size_t)4 * 12 * 12 * 4);
    half1* Xh      = (half1*)alloc((size_t)NN * 128 * 2);
    half1* Wt1     = (half1*)alloc((size_t)512 * 128 * 2);

    // CSR-build scratch aliased into CB1h (consumed before gemm_mfma writes it):
    unsigned int* tmp = (unsigned int*)CB1h;                // 6.4 MB
    int* hist_g = (int*)((char*)CB1h + (16u << 20));        // NC*NBUCK*4 = 600 KB
    int* off_g  = hist_g + NC * NBUCK;                      // 600 KB

    const int* srcp = ei;
    const int* dstp = ei + NE;
    const int NB = divup(NN, 64);

    histb_kernel<<<NC, 256, 0, stream>>>(dstp, hist_g);
    bscan1_kernel<<<1, 1024, 0, stream>>>(hist_g, bstart, row_ptr);
    boff_kernel<<<divup(NBUCK, 256), 256, 0, stream>>>(bstart, hist_g, off_g);
    binscatter_kernel<<<NC * 8, 256, 0, stream>>>(srcp, dstp, off_g, tmp);
    finalize_kernel<<<NBUCK, 256, 0, stream>>>(tmp, bstart, row_ptr, deg, cw);
    packdeg_kernel<<<divup(NE, 256), 256, 0, stream>>>(cw, deg);

    cvtx_kernel<<<divup(NN * 32, 256), 256, 0, stream>>>((const float4*)x, (half4*)Xh, NN * 32);
    prepw_kernel<<<divup(65536 + 7680 + 960 + 576, 256), 256, 0, stream>>>(
        Wl[0], Wt1, Wl[1], Wp2, Wl[2], Wp3, Wl[3], Wp4);

    // dim-64 prop (h8 gathers)
    auto prop1 = [&](const half1* feat, const half1* sub, const half1* add,
                     half1* outh, float* outf, float scale, int bnrelu,
                     const float* g, const float* bb, const float* m, const float* v) {
        proph8_kernel<<<divup(NN * 8, 256), 256, 0, stream>>>(
            (const h8*)feat, (const h8*)sub, (const h8*)add,
            (h8*)outh, (f8*)outf, row_ptr, cw, NN, scale,
            sub != nullptr, bnrelu, g, bb, m, v);
    };
    // small-dim prop (half4 gathers)
    auto prop = [&](const half1* feat, const half1* sub, const half1* add,
                    half1* outh, float* outf, int dim4, float scale,
                    int bnrelu, int used, const float* g, const float* bb,
                    const float* m, const float* v) {
        proph_kernel<<<divup(NN * dim4, 256), 256, 0, stream>>>(
            (const half4*)feat, (const half4*)sub, (const half4*)add,
            (half4*)outh, (f4*)outf, row_ptr, cw, NN, dim4, scale,
            sub != nullptr, bnrelu, used, g, bb, m, v);
    };

    // ---- layer 1 (din=128, dout=64, K=8) -> H1f ----
    gemm_mfma_kernel<<<NB, 512, 0, stream>>>(Xh, Wt1, bl[0], CB1h, NN);
    {
        auto C = [&](int k) { return (const half1*)(CB1h + (size_t)k * NN * 64); };
        prop1(C(7), nullptr, C(6), S0, nullptr, 2.f, 0, 0, 0, 0, 0);
        prop1(S0, C(7), C(5), S1, nullptr, 2.f, 0, 0, 0, 0, 0);
        prop1(S1, S0, C(4), S2, nullptr, 2.f, 0, 0, 0, 0, 0);
        prop1(S2, S1, C(3), S0, nullptr, 2.f, 0, 0, 0, 0, 0);
        prop1(S0, S2, C(2), S1, nullptr, 2.f, 0, 0, 0, 0, 0);
        prop1(S1, S0, C(1), S2, nullptr, 2.f, 0, 0, 0, 0, 0);
        prop1(S2, S1, C(0), nullptr, H1f, 1.f, 1,
              bn[0][0], bn[0][1], bn[0][2], bn[0][3]);
    }

    // ---- layer 2 (din=64, dout=18 pad 20, K=6): X=H1f -> H2f ----
    gemm_smallw_kernel<6, 16, 5><<<NB, 384, 0, stream>>>(H1f, Wp2, bl[1], 18,
                                                         (half4*)CBsh, NN);
    {
        auto C = [&](int k) { return (const half1*)(CBsh + (size_t)k * NN * 20); };
        prop(C(5), nullptr, C(4), S0, nullptr, 5, 2.f, 0, 18, 0, 0, 0, 0);
        prop(S0, C(5), C(3), S1, nullptr, 5, 2.f, 0, 18, 0, 0, 0, 0);
        prop(S1, S0, C(2), S2, nullptr, 5, 2.f, 0, 18, 0, 0, 0, 0);
        prop(S2, S1, C(1), S0, nullptr, 5, 2.f, 0, 18, 0, 0, 0, 0);
        prop(S0, S2, C(0), nullptr, H2f, 5, 1.f, 1, 18,
             bn[1][0], bn[1][1], bn[1][2], bn[1][3]);
    }

    // ---- layer 3 (din=18 str20, dout=9 pad 12, K=4): X=H2f -> H3f ----
    gemm_smallw_kernel<4, 5, 3><<<NB, 256, 0, stream>>>(H2f, Wp3, bl[2], 9,
                                                        (half4*)CBsh, NN);
    {
        auto C = [&](int k) { return (const half1*)(CBsh + (size_t)k * NN * 12); };
        prop(C(3), nullptr, C(2), S0, nullptr, 3, 2.f, 0, 9, 0, 0, 0, 0);
        prop(S0, C(3), C(1), S1, nullptr, 3, 2.f, 0, 9, 0, 0, 0, 0);
        prop(S1, S0, C(0), nullptr, H3f, 3, 1.f, 1, 9,
             bn[2][0], bn[2][1], bn[2][2], bn[2][3]);
    }

    // ---- layer 4 (din=9 str12, dout=10 pad 12, K=4): X=H3f -> d_out ----
    gemm_smallw_kernel<4, 3, 3><<<NB, 256, 0, stream>>>(H3f, Wp4, bl[3], 10,
                                                        (half4*)CBsh, NN);
    {
        auto C = [&](int k) { return (const half1*)(CBsh + (size_t)k * NN * 12); };
        prop(C(3), nullptr, C(2), S0, nullptr, 3, 2.f, 0, 10, 0, 0, 0, 0);
        prop(S0, C(3), C(1), S1, nullptr, 3, 2.f, 0, 10, 0, 0, 0, 0);
        propl_kernel<<<divup(NN * 3, 256), 256, 0, stream>>>(
            (const half4*)S1, (const half4*)S0, (const half4*)CBsh,
            (float*)d_out, row_ptr, cw, NN);
    }
}